// Round 7
// baseline (504.270 us; speedup 1.0000x reference)
//
#include <hip/hip_runtime.h>
#include <hip/hip_fp16.h>
#include <stdint.h>

typedef _Float16 half8 __attribute__((ext_vector_type(8)));
typedef _Float16 half4v __attribute__((ext_vector_type(4)));
typedef float floatx4 __attribute__((ext_vector_type(4)));

// ---------------------------------------------------------------------------
// async global->LDS copy, 16B per lane. LDS dest = wave-uniform base + lane*16.
__device__ inline void gload_lds16(const void* g, void* l) {
    __builtin_amdgcn_global_load_lds(
        (const __attribute__((address_space(1))) uint32_t*)g,
        (__attribute__((address_space(3))) uint32_t*)l, 16, 0, 0);
}

// ---------------------------------------------------------------------------
// f32 -> A-style split cat [hi | lo | hi], out row stride 3*nc.
// Markidis 3-term: [a_hi|a_lo|a_hi] . [b_hi|b_hi|b_lo] = hh + lh + hl.
__global__ __launch_bounds__(256) void split_cast_a(
    const float* __restrict__ in, _Float16* __restrict__ out, int nc, int n) {
    int i = (blockIdx.x * 256 + threadIdx.x) * 4;
    if (i >= n) return;
    float4 v = *(const float4*)(in + i);
    int r = i / nc, c = i % nc;
    half4v hi, lo;
    hi[0] = (_Float16)v.x; lo[0] = (_Float16)(v.x - (float)hi[0]);
    hi[1] = (_Float16)v.y; lo[1] = (_Float16)(v.y - (float)hi[1]);
    hi[2] = (_Float16)v.z; lo[2] = (_Float16)(v.z - (float)hi[2]);
    hi[3] = (_Float16)v.w; lo[3] = (_Float16)(v.w - (float)hi[3]);
    size_t base = (size_t)r * 3 * nc;
    *(half4v*)(out + base + c) = hi;
    *(half4v*)(out + base + nc + c) = lo;
    *(half4v*)(out + base + 2 * nc + c) = hi;
}

// ---------------------------------------------------------------------------
// transpose + B-style split cat [hi | hi | lo]: out[n][...]=f(in[k][n]).
__global__ __launch_bounds__(256) void transpose_split_b(
    const float* __restrict__ in, _Float16* __restrict__ out, int dim) {
    __shared__ float tile[32][33];
    const int tx = threadIdx.x, ty = threadIdx.y;
    const int bx = blockIdx.x * 32, by = blockIdx.y * 32;
#pragma unroll
    for (int i = 0; i < 32; i += 8)
        tile[ty + i][tx] = in[(size_t)(by + ty + i) * dim + bx + tx];
    __syncthreads();
#pragma unroll
    for (int i = 0; i < 32; i += 8) {
        float v = tile[tx][ty + i];
        _Float16 hi = (_Float16)v;
        _Float16 lo = (_Float16)(v - (float)hi);
        size_t o = (size_t)(bx + ty + i) * 3 * dim + by + tx;
        out[o] = hi;
        out[o + dim] = hi;
        out[o + 2 * dim] = lo;
    }
}

// ---------------------------------------------------------------------------
// 128x128-tile GEMM (verified): C = A @ B^T. OMODE 1/3/4/5 as before.
template <int OMODE>
__global__ __launch_bounds__(256) void gemm_bt(
    const _Float16* __restrict__ A, const _Float16* __restrict__ B,
    void* __restrict__ Cout, int M, int N, int K, int lda, int ldb,
    float cscale) {
    __shared__ _Float16 As[128 * 64];
    __shared__ _Float16 Bs[128 * 64];

    const int tid  = threadIdx.x;
    const int lane = tid & 63;
    const int wid  = tid >> 6;
    const int wr   = wid >> 1;
    const int wc   = wid & 1;
    const int row0 = blockIdx.y * 128;
    const int col0 = blockIdx.x * 128;

    floatx4 acc[4][4] = {};

    const int srow   = lane >> 3;
    const int schunk = (lane & 7) ^ srow;      // source-side XOR swizzle
    const char* gA = (const char*)(A + (size_t)(row0 + wid * 8 + srow) * lda) + schunk * 16;
    const char* gB = (const char*)(B + (size_t)(col0 + wid * 8 + srow) * ldb) + schunk * 16;
    char* lA = (char*)As + (wid * 8) * 128;
    char* lB = (char*)Bs + (wid * 8) * 128;

    const int frow   = lane & 15;
    const int rxor   = frow & 7;
    const int kchunk = lane >> 4;

    const int kTiles = K >> 6;
    for (int kt = 0; kt < kTiles; ++kt) {
        const size_t kb = (size_t)(kt << 6) * 2;
#pragma unroll
        for (int r = 0; r < 4; ++r) {
            gload_lds16(gA + (size_t)(r * 32) * lda * 2 + kb, lA + r * 32 * 128);
            gload_lds16(gB + (size_t)(r * 32) * ldb * 2 + kb, lB + r * 32 * 128);
        }
        __syncthreads();
#pragma unroll
        for (int kk = 0; kk < 2; ++kk) {
            half8 af[4], bf[4];
            const int pc = ((kk * 4 + kchunk) ^ rxor) * 16;
#pragma unroll
            for (int mi = 0; mi < 4; ++mi)
                af[mi] = *(const half8*)((const char*)As + (wr * 64 + mi * 16 + frow) * 128 + pc);
#pragma unroll
            for (int ni = 0; ni < 4; ++ni)
                bf[ni] = *(const half8*)((const char*)Bs + (wc * 64 + ni * 16 + frow) * 128 + pc);
#pragma unroll
            for (int mi = 0; mi < 4; ++mi)
#pragma unroll
                for (int ni = 0; ni < 4; ++ni)
                    acc[mi][ni] = __builtin_amdgcn_mfma_f32_16x16x32_f16(
                        af[mi], bf[ni], acc[mi][ni], 0, 0, 0);
        }
        __syncthreads();
    }

    const int orow0 = row0 + wr * 64 + ((lane >> 4) << 2);
    const int ocol0 = col0 + wc * 64 + (lane & 15);
#pragma unroll
    for (int mi = 0; mi < 4; ++mi) {
#pragma unroll
        for (int ni = 0; ni < 4; ++ni) {
#pragma unroll
            for (int j = 0; j < 4; ++j) {
                const int rr = orow0 + mi * 16 + j;
                const int cc = ocol0 + ni * 16;
                const float v = acc[mi][ni][j] * cscale;
                if (OMODE == 1) {
                    ((_Float16*)Cout)[(size_t)cc * M + rr] = (_Float16)v;
                } else if (OMODE == 3) {
                    ((float*)Cout)[(size_t)rr * N + cc] = v;
                } else {
                    _Float16 hi = (_Float16)v;
                    _Float16 lo = (_Float16)(v - (float)hi);
                    _Float16* o = (_Float16*)Cout + (size_t)rr * 3 * N + cc;
                    if (OMODE == 4) { o[0] = hi; o[N] = lo; o[2 * N] = hi; }
                    else            { o[0] = hi; o[N] = hi; o[2 * N] = lo; }
                }
            }
        }
    }
}

// ---------------------------------------------------------------------------
// 256x256-tile, BK=64, 8-wave (2Mx4N), software-pipelined with COUNTED
// lgkmcnt/vmcnt (T3+T4+T5).  Named half8 fragments; NO second launch_bounds
// arg (it capped VGPR at 128 -> 87 regs/thread spilled to scratch in R5/R6).
#define SB0() __builtin_amdgcn_sched_barrier(0)
#define BAR() __builtin_amdgcn_s_barrier()
#define LGK(N) asm volatile("s_waitcnt lgkmcnt(" #N ")" ::: "memory")
#define VMC(N) asm volatile("s_waitcnt vmcnt(" #N ")" ::: "memory")
#define MFMA16(a, b, c) __builtin_amdgcn_mfma_f32_16x16x32_f16(a, b, c, 0, 0, 0)

#define STAGE(CUR, tt)                                                        \
    _Pragma("unroll")                                                         \
    for (int i_ = 0; i_ < 4; ++i_) {                                          \
        gload_lds16(gA + (size_t)(i_ * 64) * lda + (size_t)(tt) * 64,         \
                    (char*)AsL[CUR] + (wid * 8 + i_ * 64) * 128);             \
        gload_lds16(gB + (size_t)(i_ * 64) * ldb + (size_t)(tt) * 64,         \
                    (char*)BsL[CUR] + (wid * 8 + i_ * 64) * 128);             \
    }

#define RD_A(d0, d1, d2, d3, CUR, KK, MH)                                     \
    {                                                                         \
        const char* bA_ = (const char*)AsL[CUR];                              \
        const int pcA_ = (((KK) * 4 + kchunk) ^ rxor) * 16;                   \
        const int rbA_ = (wr * 128 + (MH) * 64 + frow) * 128;                 \
        d0 = *(const half8*)(bA_ + rbA_ + 0 * 2048 + pcA_);                   \
        d1 = *(const half8*)(bA_ + rbA_ + 1 * 2048 + pcA_);                   \
        d2 = *(const half8*)(bA_ + rbA_ + 2 * 2048 + pcA_);                   \
        d3 = *(const half8*)(bA_ + rbA_ + 3 * 2048 + pcA_);                   \
    }

#define RD_B(d0, d1, d2, d3, CUR, KK)                                         \
    {                                                                         \
        const char* bB_ = (const char*)BsL[CUR];                              \
        const int pcB_ = (((KK) * 4 + kchunk) ^ rxor) * 16;                   \
        const int rbB_ = (wc * 64 + frow) * 128;                              \
        d0 = *(const half8*)(bB_ + rbB_ + 0 * 2048 + pcB_);                   \
        d1 = *(const half8*)(bB_ + rbB_ + 1 * 2048 + pcB_);                   \
        d2 = *(const half8*)(bB_ + rbB_ + 2 * 2048 + pcB_);                   \
        d3 = *(const half8*)(bB_ + rbB_ + 3 * 2048 + pcB_);                   \
    }

#define MMROW(AF, B0, B1, B2, B3, R)                                          \
    acc[R][0] = MFMA16(AF, B0, acc[R][0]);                                    \
    acc[R][1] = MFMA16(AF, B1, acc[R][1]);                                    \
    acc[R][2] = MFMA16(AF, B2, acc[R][2]);                                    \
    acc[R][3] = MFMA16(AF, B3, acc[R][3]);

#define MM(A0, A1, A2, A3, B0, B1, B2, B3, MH)                                \
    __builtin_amdgcn_s_setprio(1);                                            \
    MMROW(A0, B0, B1, B2, B3, (MH) * 4 + 0)                                   \
    MMROW(A1, B0, B1, B2, B3, (MH) * 4 + 1)                                   \
    MMROW(A2, B0, B1, B2, B3, (MH) * 4 + 2)                                   \
    MMROW(A3, B0, B1, B2, B3, (MH) * 4 + 3)                                   \
    __builtin_amdgcn_s_setprio(0);

// Counted-wait ledger (outstanding ds_reads, oldest first), steady state:
//  P0 issue afO: [afE bf0 bf1 afO]=16 -> LGK(8) drains afE,bf0 -> MM(afE,bf0)
//  P1 issue afE: [bf1 afO afE]=12     -> LGK(4) drains bf1,afO -> MM(afO,bf0)
//  P2 issue afO: [afE afO]=8          -> LGK(4) drains afE     -> MM(afE,bf1)
//  P3 LGK(0); BAR (all waves done reading cur); STAGE t+2; VMC(8) (my t+1
//  loads done); BAR (ALL waves' t+1 loads done -> NXT safe, cross-wave);
//  preload next afE,bf0 (8 reads in flight under MM(afO,bf1)); reload bf1
//  after MM (WAR on bf1).
#define TILE_BODY(tt, CUR, NXT)                                               \
    RD_A(afO0, afO1, afO2, afO3, CUR, 0, 1)                                   \
    SB0(); BAR(); LGK(8); SB0();                                              \
    MM(afE0, afE1, afE2, afE3, bf00, bf01, bf02, bf03, 0)                     \
    SB0(); BAR();                                                             \
    RD_A(afE0, afE1, afE2, afE3, CUR, 1, 0)                                   \
    SB0(); BAR(); LGK(4); SB0();                                              \
    MM(afO0, afO1, afO2, afO3, bf00, bf01, bf02, bf03, 1)                     \
    SB0(); BAR();                                                             \
    RD_A(afO0, afO1, afO2, afO3, CUR, 1, 1)                                   \
    SB0(); BAR(); LGK(4); SB0();                                              \
    MM(afE0, afE1, afE2, afE3, bf10, bf11, bf12, bf13, 0)                     \
    SB0(); BAR();                                                             \
    LGK(0); SB0(); BAR();                                                     \
    if ((tt) + 2 < NT) { STAGE(CUR, (tt) + 2) VMC(8); } else { VMC(0); }      \
    SB0(); BAR();                                                             \
    if ((tt) + 1 < NT) {                                                      \
        RD_A(afE0, afE1, afE2, afE3, NXT, 0, 0)                               \
        RD_B(bf00, bf01, bf02, bf03, NXT, 0)                                  \
    }                                                                         \
    SB0();                                                                    \
    MM(afO0, afO1, afO2, afO3, bf10, bf11, bf12, bf13, 1)                     \
    SB0();                                                                    \
    if ((tt) + 1 < NT) { RD_B(bf10, bf11, bf12, bf13, NXT, 1) }               \
    SB0(); BAR();

__global__ __launch_bounds__(512) void gemm256p_bt_f32(
    const _Float16* __restrict__ A, const _Float16* __restrict__ B,
    float* __restrict__ C, int M, int N, int K, int lda, int ldb,
    float cscale) {
    __shared__ _Float16 AsL[2][256 * 64];   // 2 x 32 KiB
    __shared__ _Float16 BsL[2][256 * 64];   // 2 x 32 KiB (128 KiB total)

    const int tid  = threadIdx.x;
    const int lane = tid & 63;
    const int wid  = tid >> 6;     // 0..7
    const int wr   = wid >> 2;     // 0..1  M-half
    const int wc   = wid & 3;      // 0..3  N-quarter
    const int row0 = blockIdx.y * 256;
    const int col0 = blockIdx.x * 256;

    floatx4 acc[8][4] = {};        // static indices only (macro-unrolled)

    const int srow   = lane >> 3;
    const int schunk = (lane & 7) ^ srow;    // pre-swizzled global source
    const _Float16* gA = A + (size_t)(row0 + wid * 8 + srow) * lda + schunk * 8;
    const _Float16* gB = B + (size_t)(col0 + wid * 8 + srow) * ldb + schunk * 8;

    const int frow   = lane & 15;
    const int rxor   = frow & 7;
    const int kchunk = lane >> 4;

    const int NT = K >> 6;   // even

    half8 afE0, afE1, afE2, afE3, afO0, afO1, afO2, afO3;
    half8 bf00, bf01, bf02, bf03, bf10, bf11, bf12, bf13;

    // prologue: stage tiles 0,1; wait tile 0; preload tile0 P0 frags + B
    STAGE(0, 0)
    STAGE(1, 1)
    VMC(8);
    SB0();
    BAR();
    RD_A(afE0, afE1, afE2, afE3, 0, 0, 0)
    RD_B(bf00, bf01, bf02, bf03, 0, 0)
    RD_B(bf10, bf11, bf12, bf13, 0, 1)
    SB0();

    for (int t = 0; t < NT; t += 2) {
        TILE_BODY(t, 0, 1)
        TILE_BODY(t + 1, 1, 0)
    }

    // epilogue: D row = 4*(lane>>4)+j, col = lane&15
    const int orow0 = row0 + wr * 128 + ((lane >> 4) << 2);
    const int ocol0 = col0 + wc * 64 + frow;
#pragma unroll
    for (int mi = 0; mi < 8; ++mi) {
#pragma unroll
        for (int ni = 0; ni < 4; ++ni) {
#pragma unroll
            for (int j = 0; j < 4; ++j) {
                const int rr = orow0 + mi * 16 + j;
                const int cc = ocol0 + ni * 16;
                C[(size_t)rr * N + cc] = acc[mi][ni][j] * cscale;
            }
        }
    }
}

// ---------------------------------------------------------------------------
// row softmax over f32 S (already scaled /32), in place: writes normalized
// P = exp(s-m)/sum as f16 at the same row base (row stride ncols f32 slots).
__global__ __launch_bounds__(256) void softmax_inplace(
    float* __restrict__ S, int ncols) {
    const int row = blockIdx.x;
    float* srow = S + (size_t)row * ncols;
    const int t = threadIdx.x;

    float x[16];
#pragma unroll
    for (int q = 0; q < 4; ++q) {
        float4 v = *(float4*)(srow + t * 16 + q * 4);
        x[q * 4 + 0] = v.x; x[q * 4 + 1] = v.y;
        x[q * 4 + 2] = v.z; x[q * 4 + 3] = v.w;
    }
    float m = x[0];
#pragma unroll
    for (int j = 1; j < 16; ++j) m = fmaxf(m, x[j]);
#pragma unroll
    for (int off = 32; off; off >>= 1) m = fmaxf(m, __shfl_xor(m, off));
    __shared__ float redm[4];
    if ((t & 63) == 0) redm[t >> 6] = m;
    __syncthreads();
    m = fmaxf(fmaxf(redm[0], redm[1]), fmaxf(redm[2], redm[3]));

    float s = 0.0f;
#pragma unroll
    for (int j = 0; j < 16; ++j) {
        x[j] = __expf(x[j] - m);
        s += x[j];
    }
#pragma unroll
    for (int off = 32; off; off >>= 1) s += __shfl_xor(s, off);
    __shared__ float reds[4];
    if ((t & 63) == 0) reds[t >> 6] = s;
    __syncthreads();
    s = reds[0] + reds[1] + reds[2] + reds[3];
    const float inv = 1.0f / s;

    _Float16* prow = (_Float16*)srow;
    half8 o0, o1;
#pragma unroll
    for (int j = 0; j < 8; ++j) {
        o0[j] = (_Float16)(x[j] * inv);
        o1[j] = (_Float16)(x[8 + j] * inv);
    }
    __syncthreads();
    *(half8*)(prow + t * 16)     = o0;
    *(half8*)(prow + t * 16 + 8) = o1;
}

// ---------------------------------------------------------------------------
extern "C" void kernel_launch(void* const* d_in, const int* in_sizes, int n_in,
                              void* d_out, int out_size, void* d_ws, size_t ws_size,
                              hipStream_t stream) {
    const float* x1 = (const float*)d_in[0];
    const float* x2 = (const float*)d_in[1];
    const float* Wq = (const float*)d_in[2];
    const float* Wk = (const float*)d_in[3];
    const float* Wv = (const float*)d_in[4];
    float* out = (float*)d_out;

    const int NQ = 4096, NKV = 4096, D = 1024;

    char* ws = (char*)d_ws;
    float*    S     = (float*)ws;                       //   0..64  f32 scores -> f16 P
    _Float16* x1cat = (_Float16*)(ws);                  //   0..24  [4096][3072] A-style
    _Float16* x2cat = (_Float16*)(ws + (24u  << 20));   //  24..48  A-style
    _Float16* Wqct  = (_Float16*)(ws + (48u  << 20));   //  48..54  B-style
    _Float16* Wkct  = (_Float16*)(ws + (54u  << 20));   //  54..60
    _Float16* Wvct  = (_Float16*)(ws + (60u  << 20));   //  60..66
    _Float16* Qcat  = (_Float16*)(ws + (66u  << 20));   //  66..90  A-style
    _Float16* Kcat  = (_Float16*)(ws + (90u  << 20));   //  90..114 B-style
    _Float16* Vt    = (_Float16*)(ws + (114u << 20));   // 114..122 [1024][4096] f16

    split_cast_a<<<(NQ * D) / 1024, 256, 0, stream>>>(x1, x1cat, D, NQ * D);
    split_cast_a<<<(NKV * D) / 1024, 256, 0, stream>>>(x2, x2cat, D, NKV * D);
    dim3 tb(32, 8), tg(D / 32, D / 32);
    transpose_split_b<<<tg, tb, 0, stream>>>(Wq, Wqct, D);
    transpose_split_b<<<tg, tb, 0, stream>>>(Wk, Wkct, D);
    transpose_split_b<<<tg, tb, 0, stream>>>(Wv, Wvct, D);

    gemm_bt<4><<<dim3(D / 128, NQ  / 128), 256, 0, stream>>>(x1cat, Wqct, Qcat, NQ,  D, 3 * D, 3 * D, 3 * D, 1.0f);
    gemm_bt<5><<<dim3(D / 128, NKV / 128), 256, 0, stream>>>(x2cat, Wkct, Kcat, NKV, D, 3 * D, 3 * D, 3 * D, 1.0f);
    // V needs only f16 accuracy: use the hi segments (K=1024) of the split bufs
    gemm_bt<1><<<dim3(D / 128, NKV / 128), 256, 0, stream>>>(x2cat, Wvct, Vt,   NKV, D, D, 3 * D, 3 * D, 1.0f);

    // scores on the pipelined 256^2 kernel (16x16 = 256 blocks = 1/CU)
    gemm256p_bt_f32<<<dim3(NKV / 256, NQ / 256), 512, 0, stream>>>(
        Qcat, Kcat, S, NQ, NKV, 3 * D, 3 * D, 3 * D, 1.0f / 32.0f);

    softmax_inplace<<<NQ, 256, 0, stream>>>(S, NKV);

    gemm_bt<3><<<dim3(D / 128, NQ / 128), 256, 0, stream>>>((const _Float16*)S, Vt, out, NQ, D, NKV, 2 * NKV, NKV, 1.0f);
}

// Round 8
// 399.760 us; speedup vs baseline: 1.2614x; 1.2614x over previous
//
#include <hip/hip_runtime.h>
#include <hip/hip_fp16.h>
#include <stdint.h>

typedef _Float16 half8 __attribute__((ext_vector_type(8)));
typedef _Float16 half4v __attribute__((ext_vector_type(4)));
typedef float floatx4 __attribute__((ext_vector_type(4)));

// ---------------------------------------------------------------------------
// async global->LDS copy, 16B per lane. LDS dest = wave-uniform base + lane*16.
__device__ inline void gload_lds16(const void* g, void* l) {
    __builtin_amdgcn_global_load_lds(
        (const __attribute__((address_space(1))) uint32_t*)g,
        (__attribute__((address_space(3))) uint32_t*)l, 16, 0, 0);
}

// ---------------------------------------------------------------------------
// f32 -> A-style split cat [hi | lo | hi], out row stride 3*nc.
// Markidis 3-term: [a_hi|a_lo|a_hi] . [b_hi|b_hi|b_lo] = hh + lh + hl.
__global__ __launch_bounds__(256) void split_cast_a(
    const float* __restrict__ in, _Float16* __restrict__ out, int nc, int n) {
    int i = (blockIdx.x * 256 + threadIdx.x) * 4;
    if (i >= n) return;
    float4 v = *(const float4*)(in + i);
    int r = i / nc, c = i % nc;
    half4v hi, lo;
    hi[0] = (_Float16)v.x; lo[0] = (_Float16)(v.x - (float)hi[0]);
    hi[1] = (_Float16)v.y; lo[1] = (_Float16)(v.y - (float)hi[1]);
    hi[2] = (_Float16)v.z; lo[2] = (_Float16)(v.z - (float)hi[2]);
    hi[3] = (_Float16)v.w; lo[3] = (_Float16)(v.w - (float)hi[3]);
    size_t base = (size_t)r * 3 * nc;
    *(half4v*)(out + base + c) = hi;
    *(half4v*)(out + base + nc + c) = lo;
    *(half4v*)(out + base + 2 * nc + c) = hi;
}

// ---------------------------------------------------------------------------
// transpose + B-style split cat [hi | hi | lo]: out[n][...]=f(in[k][n]).
__global__ __launch_bounds__(256) void transpose_split_b(
    const float* __restrict__ in, _Float16* __restrict__ out, int dim) {
    __shared__ float tile[32][33];
    const int tx = threadIdx.x, ty = threadIdx.y;
    const int bx = blockIdx.x * 32, by = blockIdx.y * 32;
#pragma unroll
    for (int i = 0; i < 32; i += 8)
        tile[ty + i][tx] = in[(size_t)(by + ty + i) * dim + bx + tx];
    __syncthreads();
#pragma unroll
    for (int i = 0; i < 32; i += 8) {
        float v = tile[tx][ty + i];
        _Float16 hi = (_Float16)v;
        _Float16 lo = (_Float16)(v - (float)hi);
        size_t o = (size_t)(bx + ty + i) * 3 * dim + by + tx;
        out[o] = hi;
        out[o + dim] = hi;
        out[o + 2 * dim] = lo;
    }
}

// ---------------------------------------------------------------------------
// 128x128-tile GEMM (verified): C = A @ B^T. OMODE 1/3/4/5 as before.
template <int OMODE>
__global__ __launch_bounds__(256) void gemm_bt(
    const _Float16* __restrict__ A, const _Float16* __restrict__ B,
    void* __restrict__ Cout, int M, int N, int K, int lda, int ldb,
    float cscale) {
    __shared__ _Float16 As[128 * 64];
    __shared__ _Float16 Bs[128 * 64];

    const int tid  = threadIdx.x;
    const int lane = tid & 63;
    const int wid  = tid >> 6;
    const int wr   = wid >> 1;
    const int wc   = wid & 1;
    const int row0 = blockIdx.y * 128;
    const int col0 = blockIdx.x * 128;

    floatx4 acc[4][4] = {};

    const int srow   = lane >> 3;
    const int schunk = (lane & 7) ^ srow;      // source-side XOR swizzle
    const char* gA = (const char*)(A + (size_t)(row0 + wid * 8 + srow) * lda) + schunk * 16;
    const char* gB = (const char*)(B + (size_t)(col0 + wid * 8 + srow) * ldb) + schunk * 16;
    char* lA = (char*)As + (wid * 8) * 128;
    char* lB = (char*)Bs + (wid * 8) * 128;

    const int frow   = lane & 15;
    const int rxor   = frow & 7;
    const int kchunk = lane >> 4;

    const int kTiles = K >> 6;
    for (int kt = 0; kt < kTiles; ++kt) {
        const size_t kb = (size_t)(kt << 6) * 2;
#pragma unroll
        for (int r = 0; r < 4; ++r) {
            gload_lds16(gA + (size_t)(r * 32) * lda * 2 + kb, lA + r * 32 * 128);
            gload_lds16(gB + (size_t)(r * 32) * ldb * 2 + kb, lB + r * 32 * 128);
        }
        __syncthreads();
#pragma unroll
        for (int kk = 0; kk < 2; ++kk) {
            half8 af[4], bf[4];
            const int pc = ((kk * 4 + kchunk) ^ rxor) * 16;
#pragma unroll
            for (int mi = 0; mi < 4; ++mi)
                af[mi] = *(const half8*)((const char*)As + (wr * 64 + mi * 16 + frow) * 128 + pc);
#pragma unroll
            for (int ni = 0; ni < 4; ++ni)
                bf[ni] = *(const half8*)((const char*)Bs + (wc * 64 + ni * 16 + frow) * 128 + pc);
#pragma unroll
            for (int mi = 0; mi < 4; ++mi)
#pragma unroll
                for (int ni = 0; ni < 4; ++ni)
                    acc[mi][ni] = __builtin_amdgcn_mfma_f32_16x16x32_f16(
                        af[mi], bf[ni], acc[mi][ni], 0, 0, 0);
        }
        __syncthreads();
    }

    const int orow0 = row0 + wr * 64 + ((lane >> 4) << 2);
    const int ocol0 = col0 + wc * 64 + (lane & 15);
#pragma unroll
    for (int mi = 0; mi < 4; ++mi) {
#pragma unroll
        for (int ni = 0; ni < 4; ++ni) {
#pragma unroll
            for (int j = 0; j < 4; ++j) {
                const int rr = orow0 + mi * 16 + j;
                const int cc = ocol0 + ni * 16;
                const float v = acc[mi][ni][j] * cscale;
                if (OMODE == 1) {
                    ((_Float16*)Cout)[(size_t)cc * M + rr] = (_Float16)v;
                } else if (OMODE == 3) {
                    ((float*)Cout)[(size_t)rr * N + cc] = v;
                } else {
                    _Float16 hi = (_Float16)v;
                    _Float16 lo = (_Float16)(v - (float)hi);
                    _Float16* o = (_Float16*)Cout + (size_t)rr * 3 * N + cc;
                    if (OMODE == 4) { o[0] = hi; o[N] = lo; o[2 * N] = hi; }
                    else            { o[0] = hi; o[N] = hi; o[2 * N] = lo; }
                }
            }
        }
    }
}

// ---------------------------------------------------------------------------
// 256x256-tile, BK=64, 8-wave (2Mx4N), R4 register shape (8 live half8 --
// fits the 256-reg/wave budget of a 512-thread 1-block/CU kernel) + m201-style
// per-phase spreading of global_load_lds into DEAD regions of CUR:
//   B and A-rows-MH0 of CUR are dead after P2's closing barrier (their reads
//   completed via LGK(0) before that barrier) -> stage 6 loads of tile t+2
//   there; last 2 (A-MH1 chunks 1,3) after P3's final barrier (CUR fully
//   dead). vmcnt(6) in P3 drains tile t+1 while t+2's 6 stay in flight.
#define SB0() __builtin_amdgcn_sched_barrier(0)
#define BAR() __builtin_amdgcn_s_barrier()
#define LGK(N) asm volatile("s_waitcnt lgkmcnt(" #N ")" ::: "memory")
#define VMC(N) asm volatile("s_waitcnt vmcnt(" #N ")" ::: "memory")
#define MFMA16(a, b, c) __builtin_amdgcn_mfma_f32_16x16x32_f16(a, b, c, 0, 0, 0)

#define STAGE_A(cur, tt, i)                                                   \
    gload_lds16(gA + (size_t)((i) * 64) * lda + (size_t)(tt) * 64,            \
                (char*)AsL[cur] + (wid * 8 + (i) * 64) * 128);
#define STAGE_B(cur, tt, i)                                                   \
    gload_lds16(gB + (size_t)((i) * 64) * ldb + (size_t)(tt) * 64,            \
                (char*)BsL[cur] + (wid * 8 + (i) * 64) * 128);

#define RD_A(d0, d1, d2, d3, cur, KK, MH)                                     \
    {                                                                         \
        const char* bA_ = (const char*)AsL[cur];                              \
        const int pcA_ = (((KK) * 4 + kchunk) ^ rxor) * 16;                   \
        const int rbA_ = (wr * 128 + (MH) * 64 + frow) * 128;                 \
        d0 = *(const half8*)(bA_ + rbA_ + 0 * 2048 + pcA_);                   \
        d1 = *(const half8*)(bA_ + rbA_ + 1 * 2048 + pcA_);                   \
        d2 = *(const half8*)(bA_ + rbA_ + 2 * 2048 + pcA_);                   \
        d3 = *(const half8*)(bA_ + rbA_ + 3 * 2048 + pcA_);                   \
    }

#define RD_B(d0, d1, d2, d3, cur, KK)                                         \
    {                                                                         \
        const char* bB_ = (const char*)BsL[cur];                              \
        const int pcB_ = (((KK) * 4 + kchunk) ^ rxor) * 16;                   \
        const int rbB_ = (wc * 64 + frow) * 128;                              \
        d0 = *(const half8*)(bB_ + rbB_ + 0 * 2048 + pcB_);                   \
        d1 = *(const half8*)(bB_ + rbB_ + 1 * 2048 + pcB_);                   \
        d2 = *(const half8*)(bB_ + rbB_ + 2 * 2048 + pcB_);                   \
        d3 = *(const half8*)(bB_ + rbB_ + 3 * 2048 + pcB_);                   \
    }

#define MMROW(AF, R)                                                          \
    acc[R][0] = MFMA16(AF, bf0, acc[R][0]);                                   \
    acc[R][1] = MFMA16(AF, bf1, acc[R][1]);                                   \
    acc[R][2] = MFMA16(AF, bf2, acc[R][2]);                                   \
    acc[R][3] = MFMA16(AF, bf3, acc[R][3]);

#define MM(MH)                                                                \
    __builtin_amdgcn_s_setprio(1);                                            \
    MMROW(af0, (MH) * 4 + 0)                                                  \
    MMROW(af1, (MH) * 4 + 1)                                                  \
    MMROW(af2, (MH) * 4 + 2)                                                  \
    MMROW(af3, (MH) * 4 + 3)                                                  \
    __builtin_amdgcn_s_setprio(0);

__global__ __launch_bounds__(512, 2) void gemm256s_bt_f32(
    const _Float16* __restrict__ A, const _Float16* __restrict__ B,
    float* __restrict__ C, int M, int N, int K, int lda, int ldb,
    float cscale) {
    __shared__ _Float16 AsL[2][256 * 64];   // 2 x 32 KiB
    __shared__ _Float16 BsL[2][256 * 64];   // 2 x 32 KiB (128 KiB total)

    const int tid  = threadIdx.x;
    const int lane = tid & 63;
    const int wid  = tid >> 6;     // 0..7
    const int wr   = wid >> 2;     // 0..1  M-half
    const int wc   = wid & 3;      // 0..3  N-quarter
    const int row0 = blockIdx.y * 256;
    const int col0 = blockIdx.x * 256;

    floatx4 acc[8][4] = {};        // static indices only (macro-unrolled)

    const int srow   = lane >> 3;
    const int schunk = (lane & 7) ^ srow;    // pre-swizzled global source
    const _Float16* gA = A + (size_t)(row0 + wid * 8 + srow) * lda + schunk * 8;
    const _Float16* gB = B + (size_t)(col0 + wid * 8 + srow) * ldb + schunk * 8;

    const int frow   = lane & 15;
    const int rxor   = frow & 7;
    const int kchunk = lane >> 4;

    const int NT = K >> 6;

    half8 af0, af1, af2, af3, bf0, bf1, bf2, bf3;

    // prologue: stage tiles 0,1; wait tile 0 (tile 1's 8 stay in flight)
#pragma unroll
    for (int i = 0; i < 4; ++i) { STAGE_A(0, 0, i) STAGE_B(0, 0, i) }
#pragma unroll
    for (int i = 0; i < 4; ++i) { STAGE_A(1, 1, i) STAGE_B(1, 1, i) }
    VMC(8);
    SB0();
    BAR();

    for (int t = 0; t < NT; ++t) {
        const int cur = t & 1;
        const bool pf = (t + 2 < NT);

        // P0: A(kk0,MH0) + B(kk0)
        RD_A(af0, af1, af2, af3, cur, 0, 0)
        RD_B(bf0, bf1, bf2, bf3, cur, 0)
        SB0(); BAR(); LGK(0); SB0();
        MM(0)
        SB0(); BAR();

        // P1: A(kk0,MH1), reuse B(kk0)
        RD_A(af0, af1, af2, af3, cur, 0, 1)
        SB0(); BAR(); LGK(0); SB0();
        MM(1)
        SB0(); BAR();

        // P2: A(kk1,MH0) + B(kk1)
        RD_A(af0, af1, af2, af3, cur, 1, 0)
        RD_B(bf0, bf1, bf2, bf3, cur, 1)
        SB0(); BAR(); LGK(0); SB0();
        MM(0)
        SB0(); BAR();

        // P3: stage-6 of tile t+2 into dead regions of cur (B all, A chunks
        // 0,2 = rows MH0); read A(kk1,MH1) = chunks 1,3 (disjoint).
        if (pf) {
            STAGE_B(cur, t + 2, 0) STAGE_B(cur, t + 2, 1)
            STAGE_B(cur, t + 2, 2) STAGE_B(cur, t + 2, 3)
            STAGE_A(cur, t + 2, 0) STAGE_A(cur, t + 2, 2)
        }
        RD_A(af0, af1, af2, af3, cur, 1, 1)
        SB0(); BAR(); LGK(0); SB0();
        if (pf) { VMC(6); } else { VMC(0); }   // drain tile t+1; t+2's 6 fly
        SB0();
        MM(1)
        SB0(); BAR();
        // cur fully dead now: last 2 chunks of tile t+2 (A rows MH1)
        if (pf) { STAGE_A(cur, t + 2, 1) STAGE_A(cur, t + 2, 3) }
    }

    // epilogue: D row = 4*(lane>>4)+j, col = lane&15
    const int orow0 = row0 + wr * 128 + ((lane >> 4) << 2);
    const int ocol0 = col0 + wc * 64 + frow;
#pragma unroll
    for (int mi = 0; mi < 8; ++mi) {
#pragma unroll
        for (int ni = 0; ni < 4; ++ni) {
#pragma unroll
            for (int j = 0; j < 4; ++j) {
                const int rr = orow0 + mi * 16 + j;
                const int cc = ocol0 + ni * 16;
                C[(size_t)rr * N + cc] = acc[mi][ni][j] * cscale;
            }
        }
    }
}

// ---------------------------------------------------------------------------
// row softmax over f32 S (already scaled /32), in place: writes normalized
// P = exp(s-m)/sum as f16 at the same row base (row stride ncols f32 slots).
__global__ __launch_bounds__(256) void softmax_inplace(
    float* __restrict__ S, int ncols) {
    const int row = blockIdx.x;
    float* srow = S + (size_t)row * ncols;
    const int t = threadIdx.x;

    float x[16];
#pragma unroll
    for (int q = 0; q < 4; ++q) {
        float4 v = *(float4*)(srow + t * 16 + q * 4);
        x[q * 4 + 0] = v.x; x[q * 4 + 1] = v.y;
        x[q * 4 + 2] = v.z; x[q * 4 + 3] = v.w;
    }
    float m = x[0];
#pragma unroll
    for (int j = 1; j < 16; ++j) m = fmaxf(m, x[j]);
#pragma unroll
    for (int off = 32; off; off >>= 1) m = fmaxf(m, __shfl_xor(m, off));
    __shared__ float redm[4];
    if ((t & 63) == 0) redm[t >> 6] = m;
    __syncthreads();
    m = fmaxf(fmaxf(redm[0], redm[1]), fmaxf(redm[2], redm[3]));

    float s = 0.0f;
#pragma unroll
    for (int j = 0; j < 16; ++j) {
        x[j] = __expf(x[j] - m);
        s += x[j];
    }
#pragma unroll
    for (int off = 32; off; off >>= 1) s += __shfl_xor(s, off);
    __shared__ float reds[4];
    if ((t & 63) == 0) reds[t >> 6] = s;
    __syncthreads();
    s = reds[0] + reds[1] + reds[2] + reds[3];
    const float inv = 1.0f / s;

    _Float16* prow = (_Float16*)srow;
    half8 o0, o1;
#pragma unroll
    for (int j = 0; j < 8; ++j) {
        o0[j] = (_Float16)(x[j] * inv);
        o1[j] = (_Float16)(x[8 + j] * inv);
    }
    __syncthreads();
    *(half8*)(prow + t * 16)     = o0;
    *(half8*)(prow + t * 16 + 8) = o1;
}

// ---------------------------------------------------------------------------
extern "C" void kernel_launch(void* const* d_in, const int* in_sizes, int n_in,
                              void* d_out, int out_size, void* d_ws, size_t ws_size,
                              hipStream_t stream) {
    const float* x1 = (const float*)d_in[0];
    const float* x2 = (const float*)d_in[1];
    const float* Wq = (const float*)d_in[2];
    const float* Wk = (const float*)d_in[3];
    const float* Wv = (const float*)d_in[4];
    float* out = (float*)d_out;

    const int NQ = 4096, NKV = 4096, D = 1024;

    char* ws = (char*)d_ws;
    float*    S     = (float*)ws;                       //   0..64  f32 scores -> f16 P
    _Float16* x1cat = (_Float16*)(ws);                  //   0..24  [4096][3072] A-style
    _Float16* x2cat = (_Float16*)(ws + (24u  << 20));   //  24..48  A-style
    _Float16* Wqct  = (_Float16*)(ws + (48u  << 20));   //  48..54  B-style
    _Float16* Wkct  = (_Float16*)(ws + (54u  << 20));   //  54..60
    _Float16* Wvct  = (_Float16*)(ws + (60u  << 20));   //  60..66
    _Float16* Qcat  = (_Float16*)(ws + (66u  << 20));   //  66..90  A-style
    _Float16* Kcat  = (_Float16*)(ws + (90u  << 20));   //  90..114 B-style
    _Float16* Vt    = (_Float16*)(ws + (114u << 20));   // 114..122 [1024][4096] f16

    split_cast_a<<<(NQ * D) / 1024, 256, 0, stream>>>(x1, x1cat, D, NQ * D);
    split_cast_a<<<(NKV * D) / 1024, 256, 0, stream>>>(x2, x2cat, D, NKV * D);
    dim3 tb(32, 8), tg(D / 32, D / 32);
    transpose_split_b<<<tg, tb, 0, stream>>>(Wq, Wqct, D);
    transpose_split_b<<<tg, tb, 0, stream>>>(Wk, Wkct, D);
    transpose_split_b<<<tg, tb, 0, stream>>>(Wv, Wvct, D);

    gemm_bt<4><<<dim3(D / 128, NQ  / 128), 256, 0, stream>>>(x1cat, Wqct, Qcat, NQ,  D, 3 * D, 3 * D, 3 * D, 1.0f);
    gemm_bt<5><<<dim3(D / 128, NKV / 128), 256, 0, stream>>>(x2cat, Wkct, Kcat, NKV, D, 3 * D, 3 * D, 3 * D, 1.0f);
    // V needs only f16 accuracy: use the hi segments (K=1024) of the split bufs
    gemm_bt<1><<<dim3(D / 128, NKV / 128), 256, 0, stream>>>(x2cat, Wvct, Vt,   NKV, D, D, 3 * D, 3 * D, 1.0f);

    // scores on the spread-staging 256^2 kernel (16x16 = 256 blocks = 1/CU)
    gemm256s_bt_f32<<<dim3(NKV / 256, NQ / 256), 512, 0, stream>>>(
        Qcat, Kcat, S, NQ, NKV, 3 * D, 3 * D, 3 * D, 1.0f / 32.0f);

    softmax_inplace<<<NQ, 256, 0, stream>>>(S, NKV);

    gemm_bt<3><<<dim3(D / 128, NQ / 128), 256, 0, stream>>>((const _Float16*)S, Vt, out, NQ, D, NKV, 2 * NKV, NKV, 1.0f);
}

// Round 9
// 371.324 us; speedup vs baseline: 1.3580x; 1.0766x over previous
//
#include <hip/hip_runtime.h>
#include <hip/hip_fp16.h>
#include <stdint.h>

typedef _Float16 half8 __attribute__((ext_vector_type(8)));
typedef _Float16 half4v __attribute__((ext_vector_type(4)));
typedef float floatx4 __attribute__((ext_vector_type(4)));

// ---------------------------------------------------------------------------
// async global->LDS copy, 16B per lane. LDS dest = wave-uniform base + lane*16.
__device__ inline void gload_lds16(const void* g, void* l) {
    __builtin_amdgcn_global_load_lds(
        (const __attribute__((address_space(1))) uint32_t*)g,
        (__attribute__((address_space(3))) uint32_t*)l, 16, 0, 0);
}

// ---------------------------------------------------------------------------
// f32 -> A-style split cat [hi | lo | hi] for TWO inputs whose outputs are
// contiguous ([2*nrows][3*nc]).  Markidis 3-term vs B-style [hi|hi|lo].
__global__ __launch_bounds__(256) void split_cast_a2(
    const float* __restrict__ in1, const float* __restrict__ in2,
    _Float16* __restrict__ out, int nc, int n1, int ntot) {
    int i = (blockIdx.x * 256 + threadIdx.x) * 4;
    if (i >= ntot) return;
    const float* src = (i < n1) ? (in1 + i) : (in2 + (i - n1));
    float4 v = *(const float4*)src;
    int r = i / nc, c = i % nc;
    half4v hi, lo;
    hi[0] = (_Float16)v.x; lo[0] = (_Float16)(v.x - (float)hi[0]);
    hi[1] = (_Float16)v.y; lo[1] = (_Float16)(v.y - (float)hi[1]);
    hi[2] = (_Float16)v.z; lo[2] = (_Float16)(v.z - (float)hi[2]);
    hi[3] = (_Float16)v.w; lo[3] = (_Float16)(v.w - (float)hi[3]);
    size_t base = (size_t)r * 3 * nc;
    *(half4v*)(out + base + c) = hi;
    *(half4v*)(out + base + nc + c) = lo;
    *(half4v*)(out + base + 2 * nc + c) = hi;
}

// ---------------------------------------------------------------------------
// transpose + B-style split cat [hi | hi | lo] for THREE dim x dim weights;
// blockIdx.z selects input; outputs contiguous ([3][dim][3*dim]).
__global__ __launch_bounds__(256) void transpose_split_b3(
    const float* __restrict__ W0, const float* __restrict__ W1,
    const float* __restrict__ W2, _Float16* __restrict__ out, int dim) {
    __shared__ float tile[32][33];
    const int z = blockIdx.z;
    const float* in = (z == 0) ? W0 : ((z == 1) ? W1 : W2);
    _Float16* o3 = out + (size_t)z * dim * 3 * dim;
    const int tx = threadIdx.x, ty = threadIdx.y;
    const int bx = blockIdx.x * 32, by = blockIdx.y * 32;
#pragma unroll
    for (int i = 0; i < 32; i += 8)
        tile[ty + i][tx] = in[(size_t)(by + ty + i) * dim + bx + tx];
    __syncthreads();
#pragma unroll
    for (int i = 0; i < 32; i += 8) {
        float v = tile[tx][ty + i];
        _Float16 hi = (_Float16)v;
        _Float16 lo = (_Float16)(v - (float)hi);
        size_t o = (size_t)(bx + ty + i) * 3 * dim + by + tx;
        o3[o] = hi;
        o3[o + dim] = hi;
        o3[o + 2 * dim] = lo;
    }
}

// ---------------------------------------------------------------------------
// 128x128-tile GEMM (verified): C = A @ B^T. OMODE 1/3/4/5 as before.
template <int OMODE>
__global__ __launch_bounds__(256) void gemm_bt(
    const _Float16* __restrict__ A, const _Float16* __restrict__ B,
    void* __restrict__ Cout, int M, int N, int K, int lda, int ldb,
    float cscale) {
    __shared__ _Float16 As[128 * 64];
    __shared__ _Float16 Bs[128 * 64];

    const int tid  = threadIdx.x;
    const int lane = tid & 63;
    const int wid  = tid >> 6;
    const int wr   = wid >> 1;
    const int wc   = wid & 1;
    const int row0 = blockIdx.y * 128;
    const int col0 = blockIdx.x * 128;

    floatx4 acc[4][4] = {};

    const int srow   = lane >> 3;
    const int schunk = (lane & 7) ^ srow;      // source-side XOR swizzle
    const char* gA = (const char*)(A + (size_t)(row0 + wid * 8 + srow) * lda) + schunk * 16;
    const char* gB = (const char*)(B + (size_t)(col0 + wid * 8 + srow) * ldb) + schunk * 16;
    char* lA = (char*)As + (wid * 8) * 128;
    char* lB = (char*)Bs + (wid * 8) * 128;

    const int frow   = lane & 15;
    const int rxor   = frow & 7;
    const int kchunk = lane >> 4;

    const int kTiles = K >> 6;
    for (int kt = 0; kt < kTiles; ++kt) {
        const size_t kb = (size_t)(kt << 6) * 2;
#pragma unroll
        for (int r = 0; r < 4; ++r) {
            gload_lds16(gA + (size_t)(r * 32) * lda * 2 + kb, lA + r * 32 * 128);
            gload_lds16(gB + (size_t)(r * 32) * ldb * 2 + kb, lB + r * 32 * 128);
        }
        __syncthreads();
#pragma unroll
        for (int kk = 0; kk < 2; ++kk) {
            half8 af[4], bf[4];
            const int pc = ((kk * 4 + kchunk) ^ rxor) * 16;
#pragma unroll
            for (int mi = 0; mi < 4; ++mi)
                af[mi] = *(const half8*)((const char*)As + (wr * 64 + mi * 16 + frow) * 128 + pc);
#pragma unroll
            for (int ni = 0; ni < 4; ++ni)
                bf[ni] = *(const half8*)((const char*)Bs + (wc * 64 + ni * 16 + frow) * 128 + pc);
#pragma unroll
            for (int mi = 0; mi < 4; ++mi)
#pragma unroll
                for (int ni = 0; ni < 4; ++ni)
                    acc[mi][ni] = __builtin_amdgcn_mfma_f32_16x16x32_f16(
                        af[mi], bf[ni], acc[mi][ni], 0, 0, 0);
        }
        __syncthreads();
    }

    const int orow0 = row0 + wr * 64 + ((lane >> 4) << 2);
    const int ocol0 = col0 + wc * 64 + (lane & 15);
#pragma unroll
    for (int mi = 0; mi < 4; ++mi) {
#pragma unroll
        for (int ni = 0; ni < 4; ++ni) {
#pragma unroll
            for (int j = 0; j < 4; ++j) {
                const int rr = orow0 + mi * 16 + j;
                const int cc = ocol0 + ni * 16;
                const float v = acc[mi][ni][j] * cscale;
                if (OMODE == 1) {
                    ((_Float16*)Cout)[(size_t)cc * M + rr] = (_Float16)v;
                } else if (OMODE == 3) {
                    ((float*)Cout)[(size_t)rr * N + cc] = v;
                } else {
                    _Float16 hi = (_Float16)v;
                    _Float16 lo = (_Float16)(v - (float)hi);
                    _Float16* o = (_Float16*)Cout + (size_t)rr * 3 * N + cc;
                    if (OMODE == 4) { o[0] = hi; o[N] = lo; o[2 * N] = hi; }
                    else            { o[0] = hi; o[N] = hi; o[2 * N] = lo; }
                }
            }
        }
    }
}

// ---------------------------------------------------------------------------
// 256x256-tile, BK=64, 8-wave (2Mx4N), serial 4-phase schedule with burst
// prefetch + counted vmcnt (R4-verified: 117 us, VGPR 100, no scratch).
// Per K-tile: 4 phases {reads -> barrier -> lgkmcnt(0) -> prio MFMA -> barrier};
// phase 3 drains all reads of buf[d] (LGK(0)+BAR), stages tile t+2 into buf[d],
// then vmcnt(8) guarantees tile t+1 resident before the closing barrier
// (every wave waits its own 8 loads, barrier publishes all).
#define SB0() __builtin_amdgcn_sched_barrier(0)

#define PH_READS(KK, MH, DO_B)                                                \
    {                                                                         \
        const int pc_ = (((KK) * 4 + kchunk) ^ rxor) * 16;                    \
        if (DO_B) {                                                           \
            _Pragma("unroll")                                                 \
            for (int ni = 0; ni < 4; ++ni)                                    \
                bf[ni] = *(const half8*)(bsB + (wc * 64 + ni * 16 + frow) * 128 + pc_); \
        }                                                                     \
        _Pragma("unroll")                                                     \
        for (int mi = 0; mi < 4; ++mi)                                        \
            af[mi] = *(const half8*)(bsA + (wr * 128 + ((MH) * 4 + mi) * 16 + frow) * 128 + pc_); \
    }

#define PH_MFMA(MH)                                                           \
    __builtin_amdgcn_s_setprio(1);                                            \
    _Pragma("unroll")                                                         \
    for (int mi = 0; mi < 4; ++mi)                                            \
        _Pragma("unroll")                                                     \
        for (int ni = 0; ni < 4; ++ni)                                        \
            acc[(MH) * 4 + mi][ni] = __builtin_amdgcn_mfma_f32_16x16x32_f16(  \
                af[mi], bf[ni], acc[(MH) * 4 + mi][ni], 0, 0, 0);             \
    __builtin_amdgcn_s_setprio(0);

__global__ __launch_bounds__(512, 2) void gemm256_bt_f32(
    const _Float16* __restrict__ A, const _Float16* __restrict__ B,
    float* __restrict__ C, int M, int N, int K, int lda, int ldb,
    float cscale) {
    __shared__ _Float16 As[2][256 * 64];   // 2 x 32 KiB
    __shared__ _Float16 Bs[2][256 * 64];   // 2 x 32 KiB  (total 128 KiB)

    const int tid  = threadIdx.x;
    const int lane = tid & 63;
    const int wid  = tid >> 6;     // 0..7
    const int wr   = wid >> 2;     // 0..1  M-half
    const int wc   = wid & 3;      // 0..3  N-quarter
    const int row0 = blockIdx.y * 256;
    const int col0 = blockIdx.x * 256;

    floatx4 acc[8][4] = {};

    // staging: instr i covers rows [wid*8 + i*64 .. +7]; lane>>3=row, lane&7=chunk
    const int srow   = lane >> 3;
    const int schunk = (lane & 7) ^ srow;    // pre-swizzled global source
    const _Float16* gA = A + (size_t)(row0 + wid * 8 + srow) * lda + schunk * 8;
    const _Float16* gB = B + (size_t)(col0 + wid * 8 + srow) * ldb + schunk * 8;

    const int frow   = lane & 15;
    const int rxor   = frow & 7;
    const int kchunk = lane >> 4;

    const int NT = K >> 6;

    auto STAGE = [&](char* lA, char* lB, int t) {
#pragma unroll
        for (int i = 0; i < 4; ++i) {
            gload_lds16(gA + (size_t)(i * 64) * lda + (size_t)t * 64,
                        lA + (wid * 8 + i * 64) * 128);
            gload_lds16(gB + (size_t)(i * 64) * ldb + (size_t)t * 64,
                        lB + (wid * 8 + i * 64) * 128);
        }
    };

    // prologue: stage tiles 0 and 1; wait tile 0 (8 youngest still allowed)
    STAGE((char*)As[0], (char*)Bs[0], 0);
    if (NT > 1) STAGE((char*)As[1], (char*)Bs[1], 1);
    asm volatile("s_waitcnt vmcnt(8)" ::: "memory");
    SB0();
    __builtin_amdgcn_s_barrier();

    half8 af[4], bf[4];
    for (int t = 0; t < NT; ++t) {
        const int d = t & 1;
        const char* bsA = (const char*)As[0] + d * (256 * 64 * 2);
        const char* bsB = (const char*)Bs[0] + d * (256 * 64 * 2);

        // ---- phase 0: kk=0, M-half 0 (+ B for kk=0)
        PH_READS(0, 0, true)
        SB0();
        __builtin_amdgcn_s_barrier();
        asm volatile("s_waitcnt lgkmcnt(0)" ::: "memory");
        SB0();
        PH_MFMA(0)
        __builtin_amdgcn_s_barrier();

        // ---- phase 1: kk=0, M-half 1
        PH_READS(0, 1, false)
        SB0();
        __builtin_amdgcn_s_barrier();
        asm volatile("s_waitcnt lgkmcnt(0)" ::: "memory");
        SB0();
        PH_MFMA(1)
        __builtin_amdgcn_s_barrier();

        // ---- phase 2: kk=1, M-half 0 (+ B for kk=1)
        PH_READS(1, 0, true)
        SB0();
        __builtin_amdgcn_s_barrier();
        asm volatile("s_waitcnt lgkmcnt(0)" ::: "memory");
        SB0();
        PH_MFMA(0)
        __builtin_amdgcn_s_barrier();

        // ---- phase 3: kk=1, M-half 1; stage t+2; counted vmcnt
        PH_READS(1, 1, false)
        asm volatile("s_waitcnt lgkmcnt(0)" ::: "memory");  // my reads done
        SB0();
        __builtin_amdgcn_s_barrier();                       // ALL reads of buf[d] done
        if (t + 2 < NT) {
            STAGE((char*)As[0] + d * (256 * 64 * 2),
                  (char*)Bs[0] + d * (256 * 64 * 2), t + 2);
            asm volatile("s_waitcnt vmcnt(8)" ::: "memory"); // tile t+1 landed
        } else {
            asm volatile("s_waitcnt vmcnt(0)" ::: "memory");
        }
        SB0();
        PH_MFMA(1)
        __builtin_amdgcn_s_barrier();                       // buf[d^1] ready for t+1
    }

    // epilogue: D row = 4*(lane>>4)+j, col = lane&15
    const int orow0 = row0 + wr * 128 + ((lane >> 4) << 2);
    const int ocol0 = col0 + wc * 64 + frow;
#pragma unroll
    for (int mi = 0; mi < 8; ++mi) {
#pragma unroll
        for (int ni = 0; ni < 4; ++ni) {
#pragma unroll
            for (int j = 0; j < 4; ++j) {
                const int rr = orow0 + mi * 16 + j;
                const int cc = ocol0 + ni * 16;
                C[(size_t)rr * N + cc] = acc[mi][ni][j] * cscale;
            }
        }
    }
}

// ---------------------------------------------------------------------------
// row softmax over f32 S (already scaled /32), in place: writes normalized
// P = exp(s-m)/sum as f16 at the same row base (row stride ncols f32 slots).
__global__ __launch_bounds__(256) void softmax_inplace(
    float* __restrict__ S, int ncols) {
    const int row = blockIdx.x;
    float* srow = S + (size_t)row * ncols;
    const int t = threadIdx.x;

    float x[16];
#pragma unroll
    for (int q = 0; q < 4; ++q) {
        float4 v = *(float4*)(srow + t * 16 + q * 4);
        x[q * 4 + 0] = v.x; x[q * 4 + 1] = v.y;
        x[q * 4 + 2] = v.z; x[q * 4 + 3] = v.w;
    }
    float m = x[0];
#pragma unroll
    for (int j = 1; j < 16; ++j) m = fmaxf(m, x[j]);
#pragma unroll
    for (int off = 32; off; off >>= 1) m = fmaxf(m, __shfl_xor(m, off));
    __shared__ float redm[4];
    if ((t & 63) == 0) redm[t >> 6] = m;
    __syncthreads();
    m = fmaxf(fmaxf(redm[0], redm[1]), fmaxf(redm[2], redm[3]));

    float s = 0.0f;
#pragma unroll
    for (int j = 0; j < 16; ++j) {
        x[j] = __expf(x[j] - m);
        s += x[j];
    }
#pragma unroll
    for (int off = 32; off; off >>= 1) s += __shfl_xor(s, off);
    __shared__ float reds[4];
    if ((t & 63) == 0) reds[t >> 6] = s;
    __syncthreads();
    s = reds[0] + reds[1] + reds[2] + reds[3];
    const float inv = 1.0f / s;

    _Float16* prow = (_Float16*)srow;
    half8 o0, o1;
#pragma unroll
    for (int j = 0; j < 8; ++j) {
        o0[j] = (_Float16)(x[j] * inv);
        o1[j] = (_Float16)(x[8 + j] * inv);
    }
    __syncthreads();
    *(half8*)(prow + t * 16)     = o0;
    *(half8*)(prow + t * 16 + 8) = o1;
}

// ---------------------------------------------------------------------------
extern "C" void kernel_launch(void* const* d_in, const int* in_sizes, int n_in,
                              void* d_out, int out_size, void* d_ws, size_t ws_size,
                              hipStream_t stream) {
    const float* x1 = (const float*)d_in[0];
    const float* x2 = (const float*)d_in[1];
    const float* Wq = (const float*)d_in[2];
    const float* Wk = (const float*)d_in[3];
    const float* Wv = (const float*)d_in[4];
    float* out = (float*)d_out;

    const int NQ = 4096, NKV = 4096, D = 1024;

    char* ws = (char*)d_ws;
    float*    S     = (float*)ws;                       //   0..64  f32 scores -> f16 P
    _Float16* xcat  = (_Float16*)(ws);                  //   0..48  [8192][3072] A-style (x1|x2)
    _Float16* x1cat = xcat;                             //   0..24
    _Float16* x2cat = (_Float16*)(ws + (24u  << 20));   //  24..48
    _Float16* Wcat  = (_Float16*)(ws + (48u  << 20));   //  48..66  [3][1024][3072] B-style
    _Float16* Wqct  = (_Float16*)(ws + (48u  << 20));   //  48..54
    _Float16* Wkct  = (_Float16*)(ws + (54u  << 20));   //  54..60
    _Float16* Wvct  = (_Float16*)(ws + (60u  << 20));   //  60..66
    _Float16* Qcat  = (_Float16*)(ws + (66u  << 20));   //  66..90  A-style
    _Float16* Kcat  = (_Float16*)(ws + (90u  << 20));   //  90..114 B-style
    _Float16* Vt    = (_Float16*)(ws + (114u << 20));   // 114..122 [1024][4096] f16

    // 1) fused split casts (x1,x2 -> contiguous xcat) + fused W transposes
    split_cast_a2<<<(2 * NQ * D) / 1024, 256, 0, stream>>>(
        x1, x2, xcat, D, NQ * D, 2 * NQ * D);
    dim3 tb(32, 8), tg3(D / 32, D / 32, 3);
    transpose_split_b3<<<tg3, tb, 0, stream>>>(Wq, Wk, Wv, Wcat, D);

    // 2) projections: Q,K split-3 K=3072; V plain f16 K=1024 (hi segments)
    gemm_bt<4><<<dim3(D / 128, NQ  / 128), 256, 0, stream>>>(x1cat, Wqct, Qcat, NQ,  D, 3 * D, 3 * D, 3 * D, 1.0f);
    gemm_bt<5><<<dim3(D / 128, NKV / 128), 256, 0, stream>>>(x2cat, Wkct, Kcat, NKV, D, 3 * D, 3 * D, 3 * D, 1.0f);
    gemm_bt<1><<<dim3(D / 128, NKV / 128), 256, 0, stream>>>(x2cat, Wvct, Vt,   NKV, D, D, 3 * D, 3 * D, 1.0f);

    // 3) scores on the R4-verified 256^2 kernel (16x16 = 256 blocks = 1/CU)
    gemm256_bt_f32<<<dim3(NKV / 256, NQ / 256), 512, 0, stream>>>(
        Qcat, Kcat, S, NQ, NKV, 3 * D, 3 * D, 3 * D, 1.0f / 32.0f);

    // 4) softmax rows in place: f32 scores -> normalized f16 P (stride 8192 f16)
    softmax_inplace<<<NQ, 256, 0, stream>>>(S, NKV);

    // 5) out = P @ V  (A = P f16, lda=8192; B^T = Vt[D][NKV], ldb=4096)
    gemm_bt<3><<<dim3(D / 128, NQ / 128), 256, 0, stream>>>((const _Float16*)S, Vt, out, NQ, D, NKV, 2 * NKV, NKV, 1.0f);
}

// Round 10
// 368.461 us; speedup vs baseline: 1.3686x; 1.0078x over previous
//
#include <hip/hip_runtime.h>
#include <hip/hip_fp16.h>
#include <stdint.h>

typedef _Float16 half8 __attribute__((ext_vector_type(8)));
typedef _Float16 half4v __attribute__((ext_vector_type(4)));
typedef float floatx4 __attribute__((ext_vector_type(4)));

// ---------------------------------------------------------------------------
// async global->LDS copy, 16B per lane. LDS dest = wave-uniform base + lane*16.
__device__ inline void gload_lds16(const void* g, void* l) {
    __builtin_amdgcn_global_load_lds(
        (const __attribute__((address_space(1))) uint32_t*)g,
        (__attribute__((address_space(3))) uint32_t*)l, 16, 0, 0);
}

// ---------------------------------------------------------------------------
// Pair split-cast: inA -> A-style [hi|lo|hi] at outA, inB -> B-style
// [hi|hi|lo] at outB. Both [n_each] elements, row width nc, out stride 3*nc.
__global__ __launch_bounds__(256) void split_cast_pair(
    const float* __restrict__ inA, _Float16* __restrict__ outA,
    const float* __restrict__ inB, _Float16* __restrict__ outB,
    int nc, int n_each) {
    int i = (blockIdx.x * 256 + threadIdx.x) * 4;
    if (i >= 2 * n_each) return;
    const bool second = (i >= n_each);
    const int ii = second ? i - n_each : i;
    const float* src = (second ? inB : inA) + ii;
    _Float16* out = second ? outB : outA;
    float4 v = *(const float4*)src;
    int r = ii / nc, c = ii % nc;
    half4v hi, lo;
    hi[0] = (_Float16)v.x; lo[0] = (_Float16)(v.x - (float)hi[0]);
    hi[1] = (_Float16)v.y; lo[1] = (_Float16)(v.y - (float)hi[1]);
    hi[2] = (_Float16)v.z; lo[2] = (_Float16)(v.z - (float)hi[2]);
    hi[3] = (_Float16)v.w; lo[3] = (_Float16)(v.w - (float)hi[3]);
    size_t base = (size_t)r * 3 * nc;
    if (!second) {  // A-style
        *(half4v*)(out + base + c) = hi;
        *(half4v*)(out + base + nc + c) = lo;
        *(half4v*)(out + base + 2 * nc + c) = hi;
    } else {        // B-style
        *(half4v*)(out + base + c) = hi;
        *(half4v*)(out + base + nc + c) = hi;
        *(half4v*)(out + base + 2 * nc + c) = lo;
    }
}

// ---------------------------------------------------------------------------
// transpose + B-style split cat [hi | hi | lo]: out[n][...]=f(in[k][n]).
__global__ __launch_bounds__(256) void transpose_split_b(
    const float* __restrict__ in, _Float16* __restrict__ out, int dim) {
    __shared__ float tile[32][33];
    const int tx = threadIdx.x, ty = threadIdx.y;
    const int bx = blockIdx.x * 32, by = blockIdx.y * 32;
#pragma unroll
    for (int i = 0; i < 32; i += 8)
        tile[ty + i][tx] = in[(size_t)(by + ty + i) * dim + bx + tx];
    __syncthreads();
#pragma unroll
    for (int i = 0; i < 32; i += 8) {
        float v = tile[tx][ty + i];
        _Float16 hi = (_Float16)v;
        _Float16 lo = (_Float16)(v - (float)hi);
        size_t o = (size_t)(bx + ty + i) * 3 * dim + by + tx;
        out[o] = hi;
        out[o + dim] = hi;
        out[o + 2 * dim] = lo;
    }
}

// ---------------------------------------------------------------------------
// 128x128-tile GEMM (verified): C = A @ B^T. OMODE 1/3/4/5 as before.
template <int OMODE>
__global__ __launch_bounds__(256) void gemm_bt(
    const _Float16* __restrict__ A, const _Float16* __restrict__ B,
    void* __restrict__ Cout, int M, int N, int K, int lda, int ldb,
    float cscale) {
    __shared__ _Float16 As[128 * 64];
    __shared__ _Float16 Bs[128 * 64];

    const int tid  = threadIdx.x;
    const int lane = tid & 63;
    const int wid  = tid >> 6;
    const int wr   = wid >> 1;
    const int wc   = wid & 1;
    const int row0 = blockIdx.y * 128;
    const int col0 = blockIdx.x * 128;

    floatx4 acc[4][4] = {};

    const int srow   = lane >> 3;
    const int schunk = (lane & 7) ^ srow;      // source-side XOR swizzle
    const char* gA = (const char*)(A + (size_t)(row0 + wid * 8 + srow) * lda) + schunk * 16;
    const char* gB = (const char*)(B + (size_t)(col0 + wid * 8 + srow) * ldb) + schunk * 16;
    char* lA = (char*)As + (wid * 8) * 128;
    char* lB = (char*)Bs + (wid * 8) * 128;

    const int frow   = lane & 15;
    const int rxor   = frow & 7;
    const int kchunk = lane >> 4;

    const int kTiles = K >> 6;
    for (int kt = 0; kt < kTiles; ++kt) {
        const size_t kb = (size_t)(kt << 6) * 2;
#pragma unroll
        for (int r = 0; r < 4; ++r) {
            gload_lds16(gA + (size_t)(r * 32) * lda * 2 + kb, lA + r * 32 * 128);
            gload_lds16(gB + (size_t)(r * 32) * ldb * 2 + kb, lB + r * 32 * 128);
        }
        __syncthreads();
#pragma unroll
        for (int kk = 0; kk < 2; ++kk) {
            half8 af[4], bf[4];
            const int pc = ((kk * 4 + kchunk) ^ rxor) * 16;
#pragma unroll
            for (int mi = 0; mi < 4; ++mi)
                af[mi] = *(const half8*)((const char*)As + (wr * 64 + mi * 16 + frow) * 128 + pc);
#pragma unroll
            for (int ni = 0; ni < 4; ++ni)
                bf[ni] = *(const half8*)((const char*)Bs + (wc * 64 + ni * 16 + frow) * 128 + pc);
#pragma unroll
            for (int mi = 0; mi < 4; ++mi)
#pragma unroll
                for (int ni = 0; ni < 4; ++ni)
                    acc[mi][ni] = __builtin_amdgcn_mfma_f32_16x16x32_f16(
                        af[mi], bf[ni], acc[mi][ni], 0, 0, 0);
        }
        __syncthreads();
    }

    const int orow0 = row0 + wr * 64 + ((lane >> 4) << 2);
    const int ocol0 = col0 + wc * 64 + (lane & 15);
#pragma unroll
    for (int mi = 0; mi < 4; ++mi) {
#pragma unroll
        for (int ni = 0; ni < 4; ++ni) {
#pragma unroll
            for (int j = 0; j < 4; ++j) {
                const int rr = orow0 + mi * 16 + j;
                const int cc = ocol0 + ni * 16;
                const float v = acc[mi][ni][j] * cscale;
                if (OMODE == 1) {
                    ((_Float16*)Cout)[(size_t)cc * M + rr] = (_Float16)v;
                } else if (OMODE == 3) {
                    ((float*)Cout)[(size_t)rr * N + cc] = v;
                } else {
                    _Float16 hi = (_Float16)v;
                    _Float16 lo = (_Float16)(v - (float)hi);
                    _Float16* o = (_Float16*)Cout + (size_t)rr * 3 * N + cc;
                    if (OMODE == 4) { o[0] = hi; o[N] = lo; o[2 * N] = hi; }
                    else            { o[0] = hi; o[N] = hi; o[2 * N] = lo; }
                }
            }
        }
    }
}

// ---------------------------------------------------------------------------
// 256x256-tile, BK=64, 8-wave (2Mx4N), serial 4-phase schedule with burst
// prefetch + counted vmcnt (R4-verified: 117 us, VGPR 100, no scratch).
#define SB0() __builtin_amdgcn_sched_barrier(0)

#define PH_READS(KK, MH, DO_B)                                                \
    {                                                                         \
        const int pc_ = (((KK) * 4 + kchunk) ^ rxor) * 16;                    \
        if (DO_B) {                                                           \
            _Pragma("unroll")                                                 \
            for (int ni = 0; ni < 4; ++ni)                                    \
                bf[ni] = *(const half8*)(bsB + (wc * 64 + ni * 16 + frow) * 128 + pc_); \
        }                                                                     \
        _Pragma("unroll")                                                     \
        for (int mi = 0; mi < 4; ++mi)                                        \
            af[mi] = *(const half8*)(bsA + (wr * 128 + ((MH) * 4 + mi) * 16 + frow) * 128 + pc_); \
    }

#define PH_MFMA(MH)                                                           \
    __builtin_amdgcn_s_setprio(1);                                            \
    _Pragma("unroll")                                                         \
    for (int mi = 0; mi < 4; ++mi)                                            \
        _Pragma("unroll")                                                     \
        for (int ni = 0; ni < 4; ++ni)                                        \
            acc[(MH) * 4 + mi][ni] = __builtin_amdgcn_mfma_f32_16x16x32_f16(  \
                af[mi], bf[ni], acc[(MH) * 4 + mi][ni], 0, 0, 0);             \
    __builtin_amdgcn_s_setprio(0);

__global__ __launch_bounds__(512, 2) void gemm256_bt_f32(
    const _Float16* __restrict__ A, const _Float16* __restrict__ B,
    float* __restrict__ C, int M, int N, int K, int lda, int ldb,
    float cscale) {
    __shared__ _Float16 As[2][256 * 64];   // 2 x 32 KiB
    __shared__ _Float16 Bs[2][256 * 64];   // 2 x 32 KiB  (total 128 KiB)

    const int tid  = threadIdx.x;
    const int lane = tid & 63;
    const int wid  = tid >> 6;     // 0..7
    const int wr   = wid >> 2;     // 0..1  M-half
    const int wc   = wid & 3;      // 0..3  N-quarter
    const int row0 = blockIdx.y * 256;
    const int col0 = blockIdx.x * 256;

    floatx4 acc[8][4] = {};

    const int srow   = lane >> 3;
    const int schunk = (lane & 7) ^ srow;    // pre-swizzled global source
    const _Float16* gA = A + (size_t)(row0 + wid * 8 + srow) * lda + schunk * 8;
    const _Float16* gB = B + (size_t)(col0 + wid * 8 + srow) * ldb + schunk * 8;

    const int frow   = lane & 15;
    const int rxor   = frow & 7;
    const int kchunk = lane >> 4;

    const int NT = K >> 6;

    auto STAGE = [&](char* lA, char* lB, int t) {
#pragma unroll
        for (int i = 0; i < 4; ++i) {
            gload_lds16(gA + (size_t)(i * 64) * lda + (size_t)t * 64,
                        lA + (wid * 8 + i * 64) * 128);
            gload_lds16(gB + (size_t)(i * 64) * ldb + (size_t)t * 64,
                        lB + (wid * 8 + i * 64) * 128);
        }
    };

    // prologue: stage tiles 0 and 1; wait tile 0 (8 youngest still allowed)
    STAGE((char*)As[0], (char*)Bs[0], 0);
    if (NT > 1) STAGE((char*)As[1], (char*)Bs[1], 1);
    asm volatile("s_waitcnt vmcnt(8)" ::: "memory");
    SB0();
    __builtin_amdgcn_s_barrier();

    half8 af[4], bf[4];
    for (int t = 0; t < NT; ++t) {
        const int d = t & 1;
        const char* bsA = (const char*)As[0] + d * (256 * 64 * 2);
        const char* bsB = (const char*)Bs[0] + d * (256 * 64 * 2);

        // ---- phase 0: kk=0, M-half 0 (+ B for kk=0)
        PH_READS(0, 0, true)
        SB0();
        __builtin_amdgcn_s_barrier();
        asm volatile("s_waitcnt lgkmcnt(0)" ::: "memory");
        SB0();
        PH_MFMA(0)
        __builtin_amdgcn_s_barrier();

        // ---- phase 1: kk=0, M-half 1
        PH_READS(0, 1, false)
        SB0();
        __builtin_amdgcn_s_barrier();
        asm volatile("s_waitcnt lgkmcnt(0)" ::: "memory");
        SB0();
        PH_MFMA(1)
        __builtin_amdgcn_s_barrier();

        // ---- phase 2: kk=1, M-half 0 (+ B for kk=1)
        PH_READS(1, 0, true)
        SB0();
        __builtin_amdgcn_s_barrier();
        asm volatile("s_waitcnt lgkmcnt(0)" ::: "memory");
        SB0();
        PH_MFMA(0)
        __builtin_amdgcn_s_barrier();

        // ---- phase 3: kk=1, M-half 1; stage t+2; counted vmcnt
        PH_READS(1, 1, false)
        asm volatile("s_waitcnt lgkmcnt(0)" ::: "memory");  // my reads done
        SB0();
        __builtin_amdgcn_s_barrier();                       // ALL reads of buf[d] done
        if (t + 2 < NT) {
            STAGE((char*)As[0] + d * (256 * 64 * 2),
                  (char*)Bs[0] + d * (256 * 64 * 2), t + 2);
            asm volatile("s_waitcnt vmcnt(8)" ::: "memory"); // tile t+1 landed
        } else {
            asm volatile("s_waitcnt vmcnt(0)" ::: "memory");
        }
        SB0();
        PH_MFMA(1)
        __builtin_amdgcn_s_barrier();                       // buf[d^1] ready for t+1
    }

    // epilogue: D row = 4*(lane>>4)+j, col = lane&15
    const int orow0 = row0 + wr * 128 + ((lane >> 4) << 2);
    const int ocol0 = col0 + wc * 64 + frow;
#pragma unroll
    for (int mi = 0; mi < 8; ++mi) {
#pragma unroll
        for (int ni = 0; ni < 4; ++ni) {
#pragma unroll
            for (int j = 0; j < 4; ++j) {
                const int rr = orow0 + mi * 16 + j;
                const int cc = ocol0 + ni * 16;
                C[(size_t)rr * N + cc] = acc[mi][ni][j] * cscale;
            }
        }
    }
}

// ---------------------------------------------------------------------------
// row softmax over f32 S (already scaled /32), in place: writes normalized
// P = exp(s-m)/sum as f16 at the same row base (row stride ncols f32 slots).
__global__ __launch_bounds__(256) void softmax_inplace(
    float* __restrict__ S, int ncols) {
    const int row = blockIdx.x;
    float* srow = S + (size_t)row * ncols;
    const int t = threadIdx.x;

    float x[16];
#pragma unroll
    for (int q = 0; q < 4; ++q) {
        float4 v = *(float4*)(srow + t * 16 + q * 4);
        x[q * 4 + 0] = v.x; x[q * 4 + 1] = v.y;
        x[q * 4 + 2] = v.z; x[q * 4 + 3] = v.w;
    }
    float m = x[0];
#pragma unroll
    for (int j = 1; j < 16; ++j) m = fmaxf(m, x[j]);
#pragma unroll
    for (int off = 32; off; off >>= 1) m = fmaxf(m, __shfl_xor(m, off));
    __shared__ float redm[4];
    if ((t & 63) == 0) redm[t >> 6] = m;
    __syncthreads();
    m = fmaxf(fmaxf(redm[0], redm[1]), fmaxf(redm[2], redm[3]));

    float s = 0.0f;
#pragma unroll
    for (int j = 0; j < 16; ++j) {
        x[j] = __expf(x[j] - m);
        s += x[j];
    }
#pragma unroll
    for (int off = 32; off; off >>= 1) s += __shfl_xor(s, off);
    __shared__ float reds[4];
    if ((t & 63) == 0) reds[t >> 6] = s;
    __syncthreads();
    s = reds[0] + reds[1] + reds[2] + reds[3];
    const float inv = 1.0f / s;

    _Float16* prow = (_Float16*)srow;
    half8 o0, o1;
#pragma unroll
    for (int j = 0; j < 8; ++j) {
        o0[j] = (_Float16)(x[j] * inv);
        o1[j] = (_Float16)(x[8 + j] * inv);
    }
    __syncthreads();
    *(half8*)(prow + t * 16)     = o0;
    *(half8*)(prow + t * 16 + 8) = o1;
}

// ---------------------------------------------------------------------------
extern "C" void kernel_launch(void* const* d_in, const int* in_sizes, int n_in,
                              void* d_out, int out_size, void* d_ws, size_t ws_size,
                              hipStream_t stream) {
    const float* x1 = (const float*)d_in[0];
    const float* x2 = (const float*)d_in[1];
    const float* Wq = (const float*)d_in[2];
    const float* Wk = (const float*)d_in[3];
    const float* Wv = (const float*)d_in[4];
    float* out = (float*)d_out;

    const int NQ = 4096, NKV = 4096, D = 1024;

    // workspace (MB).  S (0..64) overlays buffers dead before the S GEMM.
    char* ws = (char*)d_ws;
    float*    S      = (float*)ws;                       //   0..64
    _Float16* x1cat  = (_Float16*)(ws);                  //   0..24  [4096][3072] A-style (dead after T)
    _Float16* Wqcat  = (_Float16*)(ws + (24u  << 20));   //  24..30  [1024][3072] B-style (dead after Mt)
    _Float16* Wkcat  = (_Float16*)(ws + (30u  << 20));   //  30..36  [1024][3072] A-style (dead after Mt)
    _Float16* Mtcat  = (_Float16*)(ws + (36u  << 20));   //  36..42  [1024][3072] B-style (dead after T)
    _Float16* Wvct   = (_Float16*)(ws + (42u  << 20));   //  42..48  [1024][3072] B-style (dead after V)
    _Float16* x2cat  = (_Float16*)(ws + (64u  << 20));   //  64..88  [4096][3072] B-style (live thru S)
    _Float16* Tcat   = (_Float16*)(ws + (88u  << 20));   //  88..112 [4096][3072] A-style (live thru S)
    _Float16* Vt     = (_Float16*)(ws + (112u << 20));   // 112..120 [1024][4096] f16 (live thru PV)

    // 1) casts: x1 -> A-style, x2 -> B-style; Wk -> A-style, Wq -> B-style;
    //    Wv -> transposed B-style (hi segment used at K=1024)
    split_cast_pair<<<(2 * NQ * D) / 1024, 256, 0, stream>>>(
        x1, x1cat, x2, x2cat, D, NQ * D);
    split_cast_pair<<<(2 * D * D) / 1024, 256, 0, stream>>>(
        Wk, Wkcat, Wq, Wqcat, D, D * D);
    dim3 tb(32, 8), tg(D / 32, D / 32);
    transpose_split_b<<<tg, tb, 0, stream>>>(Wv, Wvct, D);

    // 2) M^T = Wk @ Wq^T  (split-3 in, B-style split out), tiny GEMM
    gemm_bt<5><<<dim3(D / 128, D / 128), 256, 0, stream>>>(
        Wkcat, Wqcat, Mtcat, D, D, 3 * D, 3 * D, 3 * D, 1.0f);

    // 3) T = x1 @ M  (A-style split out) -- replaces BOTH Q and K projections
    gemm_bt<4><<<dim3(D / 128, NQ / 128), 256, 0, stream>>>(
        x1cat, Mtcat, Tcat, NQ, D, 3 * D, 3 * D, 3 * D, 1.0f);

    // 4) V^T: plain f16, K=1024 (hi segments)
    gemm_bt<1><<<dim3(D / 128, NKV / 128), 256, 0, stream>>>(
        x2cat, Wvct, Vt, NKV, D, D, 3 * D, 3 * D, 1.0f);

    // 5) scores: S = (T @ x2^T)/32 = (Q K^T)/32, K=3072, 256^2 kernel
    gemm256_bt_f32<<<dim3(NKV / 256, NQ / 256), 512, 0, stream>>>(
        Tcat, x2cat, S, NQ, NKV, 3 * D, 3 * D, 3 * D, 1.0f / 32.0f);

    // 6) softmax rows in place: f32 scores -> normalized f16 P (stride 8192 f16)
    softmax_inplace<<<NQ, 256, 0, stream>>>(S, NKV);

    // 7) out = P @ V  (A = P f16, lda=8192; B^T = Vt[D][NKV], ldb=4096)
    gemm_bt<3><<<dim3(D / 128, NQ / 128), 256, 0, stream>>>(
        (const _Float16*)S, Vt, out, NQ, D, NKV, 2 * NKV, NKV, 1.0f);
}

// Round 11
// 325.602 us; speedup vs baseline: 1.5487x; 1.1316x over previous
//
#include <hip/hip_runtime.h>
#include <hip/hip_fp16.h>
#include <stdint.h>

typedef _Float16 half8 __attribute__((ext_vector_type(8)));
typedef _Float16 half4v __attribute__((ext_vector_type(4)));
typedef float floatx4 __attribute__((ext_vector_type(4)));

// ---------------------------------------------------------------------------
// async global->LDS copy, 16B per lane. LDS dest = wave-uniform base + lane*16.
__device__ inline void gload_lds16(const void* g, void* l) {
    __builtin_amdgcn_global_load_lds(
        (const __attribute__((address_space(1))) uint32_t*)g,
        (__attribute__((address_space(3))) uint32_t*)l, 16, 0, 0);
}

// ---------------------------------------------------------------------------
// Pair split-cast: inA -> A-style [hi|lo|hi] at outA, inB -> B-style
// [hi|hi|lo] at outB. Both [n_each] elements, row width nc, out stride 3*nc.
__global__ __launch_bounds__(256) void split_cast_pair(
    const float* __restrict__ inA, _Float16* __restrict__ outA,
    const float* __restrict__ inB, _Float16* __restrict__ outB,
    int nc, int n_each) {
    int i = (blockIdx.x * 256 + threadIdx.x) * 4;
    if (i >= 2 * n_each) return;
    const bool second = (i >= n_each);
    const int ii = second ? i - n_each : i;
    const float* src = (second ? inB : inA) + ii;
    _Float16* out = second ? outB : outA;
    float4 v = *(const float4*)src;
    int r = ii / nc, c = ii % nc;
    half4v hi, lo;
    hi[0] = (_Float16)v.x; lo[0] = (_Float16)(v.x - (float)hi[0]);
    hi[1] = (_Float16)v.y; lo[1] = (_Float16)(v.y - (float)hi[1]);
    hi[2] = (_Float16)v.z; lo[2] = (_Float16)(v.z - (float)hi[2]);
    hi[3] = (_Float16)v.w; lo[3] = (_Float16)(v.w - (float)hi[3]);
    size_t base = (size_t)r * 3 * nc;
    if (!second) {  // A-style
        *(half4v*)(out + base + c) = hi;
        *(half4v*)(out + base + nc + c) = lo;
        *(half4v*)(out + base + 2 * nc + c) = hi;
    } else {        // B-style
        *(half4v*)(out + base + c) = hi;
        *(half4v*)(out + base + nc + c) = hi;
        *(half4v*)(out + base + 2 * nc + c) = lo;
    }
}

// ---------------------------------------------------------------------------
// transpose + B-style split cat [hi | hi | lo]: out[n][...]=f(in[k][n]).
__global__ __launch_bounds__(256) void transpose_split_b(
    const float* __restrict__ in, _Float16* __restrict__ out, int dim) {
    __shared__ float tile[32][33];
    const int tx = threadIdx.x, ty = threadIdx.y;
    const int bx = blockIdx.x * 32, by = blockIdx.y * 32;
#pragma unroll
    for (int i = 0; i < 32; i += 8)
        tile[ty + i][tx] = in[(size_t)(by + ty + i) * dim + bx + tx];
    __syncthreads();
#pragma unroll
    for (int i = 0; i < 32; i += 8) {
        float v = tile[tx][ty + i];
        _Float16 hi = (_Float16)v;
        _Float16 lo = (_Float16)(v - (float)hi);
        size_t o = (size_t)(bx + ty + i) * 3 * dim + by + tx;
        out[o] = hi;
        out[o + dim] = hi;
        out[o + 2 * dim] = lo;
    }
}

// ---------------------------------------------------------------------------
// 128x128-tile, 512-thread / 8-wave (4M x 2N) GEMM: C = A @ B^T.
// Same m97 structure/LDS/swizzle as the verified 4-wave kernel; each wave
// owns a 32x64 sub-tile (acc 2x4) -> 2 waves/SIMD for wave-level overlap
// on 256-block (1 block/CU) grids.  OMODE as before.
template <int OMODE>
__global__ __launch_bounds__(512) void gemm_bt8(
    const _Float16* __restrict__ A, const _Float16* __restrict__ B,
    void* __restrict__ Cout, int M, int N, int K, int lda, int ldb,
    float cscale) {
    __shared__ _Float16 As[128 * 64];
    __shared__ _Float16 Bs[128 * 64];

    const int tid  = threadIdx.x;
    const int lane = tid & 63;
    const int wid  = tid >> 6;    // 0..7
    const int wr   = wid >> 1;    // 0..3  M-quarter (32 rows)
    const int wc   = wid & 1;     // 0..1  N-half (64 cols)
    const int row0 = blockIdx.y * 128;
    const int col0 = blockIdx.x * 128;

    floatx4 acc[2][4] = {};

    const int srow   = lane >> 3;
    const int schunk = (lane & 7) ^ srow;      // source-side XOR swizzle
    const char* gA = (const char*)(A + (size_t)(row0 + wid * 8 + srow) * lda) + schunk * 16;
    const char* gB = (const char*)(B + (size_t)(col0 + wid * 8 + srow) * ldb) + schunk * 16;
    char* lA = (char*)As + (wid * 8) * 128;
    char* lB = (char*)Bs + (wid * 8) * 128;

    const int frow   = lane & 15;
    const int rxor   = frow & 7;
    const int kchunk = lane >> 4;

    const int kTiles = K >> 6;
    for (int kt = 0; kt < kTiles; ++kt) {
        const size_t kb = (size_t)(kt << 6) * 2;
#pragma unroll
        for (int r = 0; r < 2; ++r) {
            gload_lds16(gA + (size_t)(r * 64) * lda * 2 + kb, lA + r * 64 * 128);
            gload_lds16(gB + (size_t)(r * 64) * ldb * 2 + kb, lB + r * 64 * 128);
        }
        __syncthreads();
#pragma unroll
        for (int kk = 0; kk < 2; ++kk) {
            half8 af[2], bf[4];
            const int pc = ((kk * 4 + kchunk) ^ rxor) * 16;
#pragma unroll
            for (int mi = 0; mi < 2; ++mi)
                af[mi] = *(const half8*)((const char*)As + (wr * 32 + mi * 16 + frow) * 128 + pc);
#pragma unroll
            for (int ni = 0; ni < 4; ++ni)
                bf[ni] = *(const half8*)((const char*)Bs + (wc * 64 + ni * 16 + frow) * 128 + pc);
#pragma unroll
            for (int mi = 0; mi < 2; ++mi)
#pragma unroll
                for (int ni = 0; ni < 4; ++ni)
                    acc[mi][ni] = __builtin_amdgcn_mfma_f32_16x16x32_f16(
                        af[mi], bf[ni], acc[mi][ni], 0, 0, 0);
        }
        __syncthreads();
    }

    // epilogue: D row = 4*(lane>>4)+j, col = lane&15
    const int orow0 = row0 + wr * 32 + ((lane >> 4) << 2);
    const int ocol0 = col0 + wc * 64 + (lane & 15);
#pragma unroll
    for (int mi = 0; mi < 2; ++mi) {
#pragma unroll
        for (int ni = 0; ni < 4; ++ni) {
#pragma unroll
            for (int j = 0; j < 4; ++j) {
                const int rr = orow0 + mi * 16 + j;
                const int cc = ocol0 + ni * 16;
                const float v = acc[mi][ni][j] * cscale;
                if (OMODE == 1) {
                    ((_Float16*)Cout)[(size_t)cc * M + rr] = (_Float16)v;
                } else if (OMODE == 3) {
                    ((float*)Cout)[(size_t)rr * N + cc] = v;
                } else {
                    _Float16 hi = (_Float16)v;
                    _Float16 lo = (_Float16)(v - (float)hi);
                    _Float16* o = (_Float16*)Cout + (size_t)rr * 3 * N + cc;
                    if (OMODE == 4) { o[0] = hi; o[N] = lo; o[2 * N] = hi; }
                    else            { o[0] = hi; o[N] = hi; o[2 * N] = lo; }
                }
            }
        }
    }
}

// ---------------------------------------------------------------------------
// 256x256-tile, BK=64, 8-wave (2Mx4N), serial 4-phase schedule with burst
// prefetch + counted vmcnt (R4-verified: 117 us, VGPR 100, no scratch).
#define SB0() __builtin_amdgcn_sched_barrier(0)

#define PH_READS(KK, MH, DO_B)                                                \
    {                                                                         \
        const int pc_ = (((KK) * 4 + kchunk) ^ rxor) * 16;                    \
        if (DO_B) {                                                           \
            _Pragma("unroll")                                                 \
            for (int ni = 0; ni < 4; ++ni)                                    \
                bf[ni] = *(const half8*)(bsB + (wc * 64 + ni * 16 + frow) * 128 + pc_); \
        }                                                                     \
        _Pragma("unroll")                                                     \
        for (int mi = 0; mi < 4; ++mi)                                        \
            af[mi] = *(const half8*)(bsA + (wr * 128 + ((MH) * 4 + mi) * 16 + frow) * 128 + pc_); \
    }

#define PH_MFMA(MH)                                                           \
    __builtin_amdgcn_s_setprio(1);                                            \
    _Pragma("unroll")                                                         \
    for (int mi = 0; mi < 4; ++mi)                                            \
        _Pragma("unroll")                                                     \
        for (int ni = 0; ni < 4; ++ni)                                        \
            acc[(MH) * 4 + mi][ni] = __builtin_amdgcn_mfma_f32_16x16x32_f16(  \
                af[mi], bf[ni], acc[(MH) * 4 + mi][ni], 0, 0, 0);             \
    __builtin_amdgcn_s_setprio(0);

__global__ __launch_bounds__(512, 2) void gemm256_bt_f32(
    const _Float16* __restrict__ A, const _Float16* __restrict__ B,
    float* __restrict__ C, int M, int N, int K, int lda, int ldb,
    float cscale) {
    __shared__ _Float16 As[2][256 * 64];   // 2 x 32 KiB
    __shared__ _Float16 Bs[2][256 * 64];   // 2 x 32 KiB  (total 128 KiB)

    const int tid  = threadIdx.x;
    const int lane = tid & 63;
    const int wid  = tid >> 6;     // 0..7
    const int wr   = wid >> 2;     // 0..1  M-half
    const int wc   = wid & 3;      // 0..3  N-quarter
    const int row0 = blockIdx.y * 256;
    const int col0 = blockIdx.x * 256;

    floatx4 acc[8][4] = {};

    const int srow   = lane >> 3;
    const int schunk = (lane & 7) ^ srow;    // pre-swizzled global source
    const _Float16* gA = A + (size_t)(row0 + wid * 8 + srow) * lda + schunk * 8;
    const _Float16* gB = B + (size_t)(col0 + wid * 8 + srow) * ldb + schunk * 8;

    const int frow   = lane & 15;
    const int rxor   = frow & 7;
    const int kchunk = lane >> 4;

    const int NT = K >> 6;

    auto STAGE = [&](char* lA, char* lB, int t) {
#pragma unroll
        for (int i = 0; i < 4; ++i) {
            gload_lds16(gA + (size_t)(i * 64) * lda + (size_t)t * 64,
                        lA + (wid * 8 + i * 64) * 128);
            gload_lds16(gB + (size_t)(i * 64) * ldb + (size_t)t * 64,
                        lB + (wid * 8 + i * 64) * 128);
        }
    };

    // prologue: stage tiles 0 and 1; wait tile 0 (8 youngest still allowed)
    STAGE((char*)As[0], (char*)Bs[0], 0);
    if (NT > 1) STAGE((char*)As[1], (char*)Bs[1], 1);
    asm volatile("s_waitcnt vmcnt(8)" ::: "memory");
    SB0();
    __builtin_amdgcn_s_barrier();

    half8 af[4], bf[4];
    for (int t = 0; t < NT; ++t) {
        const int d = t & 1;
        const char* bsA = (const char*)As[0] + d * (256 * 64 * 2);
        const char* bsB = (const char*)Bs[0] + d * (256 * 64 * 2);

        // ---- phase 0: kk=0, M-half 0 (+ B for kk=0)
        PH_READS(0, 0, true)
        SB0();
        __builtin_amdgcn_s_barrier();
        asm volatile("s_waitcnt lgkmcnt(0)" ::: "memory");
        SB0();
        PH_MFMA(0)
        __builtin_amdgcn_s_barrier();

        // ---- phase 1: kk=0, M-half 1
        PH_READS(0, 1, false)
        SB0();
        __builtin_amdgcn_s_barrier();
        asm volatile("s_waitcnt lgkmcnt(0)" ::: "memory");
        SB0();
        PH_MFMA(1)
        __builtin_amdgcn_s_barrier();

        // ---- phase 2: kk=1, M-half 0 (+ B for kk=1)
        PH_READS(1, 0, true)
        SB0();
        __builtin_amdgcn_s_barrier();
        asm volatile("s_waitcnt lgkmcnt(0)" ::: "memory");
        SB0();
        PH_MFMA(0)
        __builtin_amdgcn_s_barrier();

        // ---- phase 3: kk=1, M-half 1; stage t+2; counted vmcnt
        PH_READS(1, 1, false)
        asm volatile("s_waitcnt lgkmcnt(0)" ::: "memory");  // my reads done
        SB0();
        __builtin_amdgcn_s_barrier();                       // ALL reads of buf[d] done
        if (t + 2 < NT) {
            STAGE((char*)As[0] + d * (256 * 64 * 2),
                  (char*)Bs[0] + d * (256 * 64 * 2), t + 2);
            asm volatile("s_waitcnt vmcnt(8)" ::: "memory"); // tile t+1 landed
        } else {
            asm volatile("s_waitcnt vmcnt(0)" ::: "memory");
        }
        SB0();
        PH_MFMA(1)
        __builtin_amdgcn_s_barrier();                       // buf[d^1] ready for t+1
    }

    // epilogue: D row = 4*(lane>>4)+j, col = lane&15
    const int orow0 = row0 + wr * 128 + ((lane >> 4) << 2);
    const int ocol0 = col0 + wc * 64 + frow;
#pragma unroll
    for (int mi = 0; mi < 8; ++mi) {
#pragma unroll
        for (int ni = 0; ni < 4; ++ni) {
#pragma unroll
            for (int j = 0; j < 4; ++j) {
                const int rr = orow0 + mi * 16 + j;
                const int cc = ocol0 + ni * 16;
                C[(size_t)rr * N + cc] = acc[mi][ni][j] * cscale;
            }
        }
    }
}

// ---------------------------------------------------------------------------
// row softmax over f32 S (already scaled /32), in place: writes normalized
// P = exp(s-m)/sum as f16 at the same row base (row stride ncols f32 slots).
__global__ __launch_bounds__(256) void softmax_inplace(
    float* __restrict__ S, int ncols) {
    const int row = blockIdx.x;
    float* srow = S + (size_t)row * ncols;
    const int t = threadIdx.x;

    float x[16];
#pragma unroll
    for (int q = 0; q < 4; ++q) {
        float4 v = *(float4*)(srow + t * 16 + q * 4);
        x[q * 4 + 0] = v.x; x[q * 4 + 1] = v.y;
        x[q * 4 + 2] = v.z; x[q * 4 + 3] = v.w;
    }
    float m = x[0];
#pragma unroll
    for (int j = 1; j < 16; ++j) m = fmaxf(m, x[j]);
#pragma unroll
    for (int off = 32; off; off >>= 1) m = fmaxf(m, __shfl_xor(m, off));
    __shared__ float redm[4];
    if ((t & 63) == 0) redm[t >> 6] = m;
    __syncthreads();
    m = fmaxf(fmaxf(redm[0], redm[1]), fmaxf(redm[2], redm[3]));

    float s = 0.0f;
#pragma unroll
    for (int j = 0; j < 16; ++j) {
        x[j] = __expf(x[j] - m);
        s += x[j];
    }
#pragma unroll
    for (int off = 32; off; off >>= 1) s += __shfl_xor(s, off);
    __shared__ float reds[4];
    if ((t & 63) == 0) reds[t >> 6] = s;
    __syncthreads();
    s = reds[0] + reds[1] + reds[2] + reds[3];
    const float inv = 1.0f / s;

    _Float16* prow = (_Float16*)srow;
    half8 o0, o1;
#pragma unroll
    for (int j = 0; j < 8; ++j) {
        o0[j] = (_Float16)(x[j] * inv);
        o1[j] = (_Float16)(x[8 + j] * inv);
    }
    __syncthreads();
    *(half8*)(prow + t * 16)     = o0;
    *(half8*)(prow + t * 16 + 8) = o1;
}

// ---------------------------------------------------------------------------
extern "C" void kernel_launch(void* const* d_in, const int* in_sizes, int n_in,
                              void* d_out, int out_size, void* d_ws, size_t ws_size,
                              hipStream_t stream) {
    const float* x1 = (const float*)d_in[0];
    const float* x2 = (const float*)d_in[1];
    const float* Wq = (const float*)d_in[2];
    const float* Wk = (const float*)d_in[3];
    const float* Wv = (const float*)d_in[4];
    float* out = (float*)d_out;

    const int NQ = 4096, NKV = 4096, D = 1024;

    // workspace (MB).  S (0..64) overlays buffers dead before the S GEMM.
    char* ws = (char*)d_ws;
    float*    S      = (float*)ws;                       //   0..64
    _Float16* x1cat  = (_Float16*)(ws);                  //   0..24  [4096][3072] A-style (dead after T)
    _Float16* Wqcat  = (_Float16*)(ws + (24u  << 20));   //  24..30  [1024][3072] B-style (dead after Mt)
    _Float16* Wkcat  = (_Float16*)(ws + (30u  << 20));   //  30..36  [1024][3072] A-style (dead after Mt)
    _Float16* Mtcat  = (_Float16*)(ws + (36u  << 20));   //  36..42  [1024][3072] B-style (dead after T)
    _Float16* Wvct   = (_Float16*)(ws + (42u  << 20));   //  42..48  [1024][3072] B-style (dead after V)
    _Float16* x2cat  = (_Float16*)(ws + (64u  << 20));   //  64..88  [4096][3072] B-style (live thru S)
    _Float16* Tcat   = (_Float16*)(ws + (88u  << 20));   //  88..112 [4096][3072] A-style (live thru S)
    _Float16* Vt     = (_Float16*)(ws + (112u << 20));   // 112..120 [1024][4096] f16 (live thru PV)

    // 1) casts: x1 -> A-style, x2 -> B-style; Wk -> A-style, Wq -> B-style;
    //    Wv -> transposed B-style (hi segment used at K=1024)
    split_cast_pair<<<(2 * NQ * D) / 1024, 256, 0, stream>>>(
        x1, x1cat, x2, x2cat, D, NQ * D);
    split_cast_pair<<<(2 * D * D) / 1024, 256, 0, stream>>>(
        Wk, Wkcat, Wq, Wqcat, D, D * D);
    dim3 tb(32, 8), tg(D / 32, D / 32);
    transpose_split_b<<<tg, tb, 0, stream>>>(Wv, Wvct, D);

    // 2) M^T = Wk @ Wq^T  (split-3 in, B-style split out), 8-wave kernel
    gemm_bt8<5><<<dim3(D / 128, D / 128), 512, 0, stream>>>(
        Wkcat, Wqcat, Mtcat, D, D, 3 * D, 3 * D, 3 * D, 1.0f);

    // 3) T = x1 @ M  (A-style split out) -- replaces BOTH Q and K projections
    gemm_bt8<4><<<dim3(D / 128, NQ / 128), 512, 0, stream>>>(
        x1cat, Mtcat, Tcat, NQ, D, 3 * D, 3 * D, 3 * D, 1.0f);

    // 4) V^T: plain f16, K=1024 (hi segments)
    gemm_bt8<1><<<dim3(D / 128, NKV / 128), 512, 0, stream>>>(
        x2cat, Wvct, Vt, NKV, D, D, 3 * D, 3 * D, 1.0f);

    // 5) scores: S = (T @ x2^T)/32 = (Q K^T)/32, K=3072, 256^2 kernel
    gemm256_bt_f32<<<dim3(NKV / 256, NQ / 256), 512, 0, stream>>>(
        Tcat, x2cat, S, NQ, NKV, 3 * D, 3 * D, 3 * D, 1.0f / 32.0f);

    // 6) softmax rows in place: f32 scores -> normalized f16 P (stride 8192 f16)
    softmax_inplace<<<NQ, 256, 0, stream>>>(S, NKV);

    // 7) out = P @ V  (A = P f16, lda=8192; B^T = Vt[D][NKV], ldb=4096)
    gemm_bt8<3><<<dim3(D / 128, NQ / 128), 512, 0, stream>>>(
        (const _Float16*)S, Vt, out, NQ, D, NKV, 2 * NKV, NKV, 1.0f);
}

// Round 12
// 318.926 us; speedup vs baseline: 1.5811x; 1.0209x over previous
//
#include <hip/hip_runtime.h>
#include <hip/hip_fp16.h>
#include <stdint.h>

typedef _Float16 half8 __attribute__((ext_vector_type(8)));
typedef _Float16 half4v __attribute__((ext_vector_type(4)));
typedef float floatx4 __attribute__((ext_vector_type(4)));

// ---------------------------------------------------------------------------
// async global->LDS copy, 16B per lane. LDS dest = wave-uniform base + lane*16.
__device__ inline void gload_lds16(const void* g, void* l) {
    __builtin_amdgcn_global_load_lds(
        (const __attribute__((address_space(1))) uint32_t*)g,
        (__attribute__((address_space(3))) uint32_t*)l, 16, 0, 0);
}

// ---------------------------------------------------------------------------
// Pair split-cast: inA -> A-style [hi|lo|hi] at outA, inB -> B-style
// [hi|hi|lo] at outB. Both [n_each] elements, row width nc, out stride 3*nc.
__global__ __launch_bounds__(256) void split_cast_pair(
    const float* __restrict__ inA, _Float16* __restrict__ outA,
    const float* __restrict__ inB, _Float16* __restrict__ outB,
    int nc, int n_each) {
    int i = (blockIdx.x * 256 + threadIdx.x) * 4;
    if (i >= 2 * n_each) return;
    const bool second = (i >= n_each);
    const int ii = second ? i - n_each : i;
    const float* src = (second ? inB : inA) + ii;
    _Float16* out = second ? outB : outA;
    float4 v = *(const float4*)src;
    int r = ii / nc, c = ii % nc;
    half4v hi, lo;
    hi[0] = (_Float16)v.x; lo[0] = (_Float16)(v.x - (float)hi[0]);
    hi[1] = (_Float16)v.y; lo[1] = (_Float16)(v.y - (float)hi[1]);
    hi[2] = (_Float16)v.z; lo[2] = (_Float16)(v.z - (float)hi[2]);
    hi[3] = (_Float16)v.w; lo[3] = (_Float16)(v.w - (float)hi[3]);
    size_t base = (size_t)r * 3 * nc;
    if (!second) {  // A-style
        *(half4v*)(out + base + c) = hi;
        *(half4v*)(out + base + nc + c) = lo;
        *(half4v*)(out + base + 2 * nc + c) = hi;
    } else {        // B-style
        *(half4v*)(out + base + c) = hi;
        *(half4v*)(out + base + nc + c) = hi;
        *(half4v*)(out + base + 2 * nc + c) = lo;
    }
}

// ---------------------------------------------------------------------------
// transpose + B-style split cat [hi | hi | lo]: out[n][...]=f(in[k][n]).
__global__ __launch_bounds__(256) void transpose_split_b(
    const float* __restrict__ in, _Float16* __restrict__ out, int dim) {
    __shared__ float tile[32][33];
    const int tx = threadIdx.x, ty = threadIdx.y;
    const int bx = blockIdx.x * 32, by = blockIdx.y * 32;
#pragma unroll
    for (int i = 0; i < 32; i += 8)
        tile[ty + i][tx] = in[(size_t)(by + ty + i) * dim + bx + tx];
    __syncthreads();
#pragma unroll
    for (int i = 0; i < 32; i += 8) {
        float v = tile[tx][ty + i];
        _Float16 hi = (_Float16)v;
        _Float16 lo = (_Float16)(v - (float)hi);
        size_t o = (size_t)(bx + ty + i) * 3 * dim + by + tx;
        out[o] = hi;
        out[o + dim] = hi;
        out[o + 2 * dim] = lo;
    }
}

// ---------------------------------------------------------------------------
// 128x128-tile, 512-thread / 8-wave (4M x 2N) GEMM: C = A @ B^T.
// Each wave owns a 32x64 sub-tile (acc 2x4) -> 2 waves/SIMD overlap.
template <int OMODE>
__global__ __launch_bounds__(512) void gemm_bt8(
    const _Float16* __restrict__ A, const _Float16* __restrict__ B,
    void* __restrict__ Cout, int M, int N, int K, int lda, int ldb,
    float cscale) {
    __shared__ _Float16 As[128 * 64];
    __shared__ _Float16 Bs[128 * 64];

    const int tid  = threadIdx.x;
    const int lane = tid & 63;
    const int wid  = tid >> 6;    // 0..7
    const int wr   = wid >> 1;    // 0..3  M-quarter (32 rows)
    const int wc   = wid & 1;     // 0..1  N-half (64 cols)
    const int row0 = blockIdx.y * 128;
    const int col0 = blockIdx.x * 128;

    floatx4 acc[2][4] = {};

    const int srow   = lane >> 3;
    const int schunk = (lane & 7) ^ srow;      // source-side XOR swizzle
    const char* gA = (const char*)(A + (size_t)(row0 + wid * 8 + srow) * lda) + schunk * 16;
    const char* gB = (const char*)(B + (size_t)(col0 + wid * 8 + srow) * ldb) + schunk * 16;
    char* lA = (char*)As + (wid * 8) * 128;
    char* lB = (char*)Bs + (wid * 8) * 128;

    const int frow   = lane & 15;
    const int rxor   = frow & 7;
    const int kchunk = lane >> 4;

    const int kTiles = K >> 6;
    for (int kt = 0; kt < kTiles; ++kt) {
        const size_t kb = (size_t)(kt << 6) * 2;
#pragma unroll
        for (int r = 0; r < 2; ++r) {
            gload_lds16(gA + (size_t)(r * 64) * lda * 2 + kb, lA + r * 64 * 128);
            gload_lds16(gB + (size_t)(r * 64) * ldb * 2 + kb, lB + r * 64 * 128);
        }
        __syncthreads();
#pragma unroll
        for (int kk = 0; kk < 2; ++kk) {
            half8 af[2], bf[4];
            const int pc = ((kk * 4 + kchunk) ^ rxor) * 16;
#pragma unroll
            for (int mi = 0; mi < 2; ++mi)
                af[mi] = *(const half8*)((const char*)As + (wr * 32 + mi * 16 + frow) * 128 + pc);
#pragma unroll
            for (int ni = 0; ni < 4; ++ni)
                bf[ni] = *(const half8*)((const char*)Bs + (wc * 64 + ni * 16 + frow) * 128 + pc);
#pragma unroll
            for (int mi = 0; mi < 2; ++mi)
#pragma unroll
                for (int ni = 0; ni < 4; ++ni)
                    acc[mi][ni] = __builtin_amdgcn_mfma_f32_16x16x32_f16(
                        af[mi], bf[ni], acc[mi][ni], 0, 0, 0);
        }
        __syncthreads();
    }

    // epilogue: D row = 4*(lane>>4)+j, col = lane&15
    const int orow0 = row0 + wr * 32 + ((lane >> 4) << 2);
    const int ocol0 = col0 + wc * 64 + (lane & 15);
#pragma unroll
    for (int mi = 0; mi < 2; ++mi) {
#pragma unroll
        for (int ni = 0; ni < 4; ++ni) {
#pragma unroll
            for (int j = 0; j < 4; ++j) {
                const int rr = orow0 + mi * 16 + j;
                const int cc = ocol0 + ni * 16;
                const float v = acc[mi][ni][j] * cscale;
                if (OMODE == 1) {
                    ((_Float16*)Cout)[(size_t)cc * M + rr] = (_Float16)v;
                } else if (OMODE == 3) {
                    ((float*)Cout)[(size_t)rr * N + cc] = v;
                } else {
                    _Float16 hi = (_Float16)v;
                    _Float16 lo = (_Float16)(v - (float)hi);
                    _Float16* o = (_Float16*)Cout + (size_t)rr * 3 * N + cc;
                    if (OMODE == 4) { o[0] = hi; o[N] = lo; o[2 * N] = hi; }
                    else            { o[0] = hi; o[N] = hi; o[2 * N] = lo; }
                }
            }
        }
    }
}

// ---------------------------------------------------------------------------
// 256x256-tile, BK=64, 8-wave (2Mx4N), 4 phases/K-tile with PER-PHASE spread
// staging (m201/m196: reads-first, stage-second) + counted vmcnt(6).
// Dead-region schedule: P3 stages tile t+2's B + A-MH0 into buf[cur] (their
// last readers are P2, published by P2's closing barrier); next-P0 stages
// t+2's A-MH1 (dead after P3's closing barrier).  vmcnt(6) in P3 drains
// exactly tile t+1 (8 oldest of 14) before its reads begin at next-P0.
#define SB0() __builtin_amdgcn_sched_barrier(0)
#define BAR() __builtin_amdgcn_s_barrier()

#define PH_READS(KK, MH, DO_B)                                                \
    {                                                                         \
        const int pc_ = (((KK) * 4 + kchunk) ^ rxor) * 16;                    \
        if (DO_B) {                                                           \
            _Pragma("unroll")                                                 \
            for (int ni = 0; ni < 4; ++ni)                                    \
                bf[ni] = *(const half8*)(bsB + (wc * 64 + ni * 16 + frow) * 128 + pc_); \
        }                                                                     \
        _Pragma("unroll")                                                     \
        for (int mi = 0; mi < 4; ++mi)                                        \
            af[mi] = *(const half8*)(bsA + (wr * 128 + ((MH) * 4 + mi) * 16 + frow) * 128 + pc_); \
    }

#define PH_MFMA(MH)                                                           \
    __builtin_amdgcn_s_setprio(1);                                            \
    _Pragma("unroll")                                                         \
    for (int mi = 0; mi < 4; ++mi)                                            \
        _Pragma("unroll")                                                     \
        for (int ni = 0; ni < 4; ++ni)                                        \
            acc[(MH) * 4 + mi][ni] = __builtin_amdgcn_mfma_f32_16x16x32_f16(  \
                af[mi], bf[ni], acc[(MH) * 4 + mi][ni], 0, 0, 0);             \
    __builtin_amdgcn_s_setprio(0);

#define STG_A(DST, tt, i)                                                     \
    gload_lds16(gA + (size_t)((i) * 64) * lda + (size_t)(tt) * 64,            \
                (char*)(DST) + (wid * 8 + (i) * 64) * 128);
#define STG_B(DST, tt, i)                                                     \
    gload_lds16(gB + (size_t)((i) * 64) * ldb + (size_t)(tt) * 64,            \
                (char*)(DST) + (wid * 8 + (i) * 64) * 128);

__global__ __launch_bounds__(512, 2) void gemm256_bt_f32(
    const _Float16* __restrict__ A, const _Float16* __restrict__ B,
    float* __restrict__ C, int M, int N, int K, int lda, int ldb,
    float cscale) {
    __shared__ _Float16 As[2][256 * 64];   // 2 x 32 KiB
    __shared__ _Float16 Bs[2][256 * 64];   // 2 x 32 KiB  (total 128 KiB)

    const int tid  = threadIdx.x;
    const int lane = tid & 63;
    const int wid  = tid >> 6;     // 0..7
    const int wr   = wid >> 2;     // 0..1  M-half
    const int wc   = wid & 3;      // 0..3  N-quarter
    const int row0 = blockIdx.y * 256;
    const int col0 = blockIdx.x * 256;

    floatx4 acc[8][4] = {};

    const int srow   = lane >> 3;
    const int schunk = (lane & 7) ^ srow;    // pre-swizzled global source
    const _Float16* gA = A + (size_t)(row0 + wid * 8 + srow) * lda + schunk * 8;
    const _Float16* gB = B + (size_t)(col0 + wid * 8 + srow) * ldb + schunk * 8;

    const int frow   = lane & 15;
    const int rxor   = frow & 7;
    const int kchunk = lane >> 4;

    const int NT = K >> 6;

    // prologue: stage tiles 0 and 1 fully; wait tile 0 (tile 1's 8 in flight)
#pragma unroll
    for (int i = 0; i < 4; ++i) { STG_A((char*)As[0], 0, i) STG_B((char*)Bs[0], 0, i) }
#pragma unroll
    for (int i = 0; i < 4; ++i) { STG_A((char*)As[1], 1, i) STG_B((char*)Bs[1], 1, i) }
    asm volatile("s_waitcnt vmcnt(8)" ::: "memory");
    SB0();
    BAR();

    half8 af[4], bf[4];
    for (int t = 0; t < NT; ++t) {
        const int d = t & 1;
        char* curA = (char*)As[0] + d * 32768;
        char* curB = (char*)Bs[0] + d * 32768;
        char* nxtA = (char*)As[0] + (d ^ 1) * 32768;
        const char* bsA = curA;
        const char* bsB = curB;

        // ---- P0: kk0, MH0 (+B kk0); then finish staging tile t+1 (A-MH1)
        PH_READS(0, 0, true)
        if (t >= 1 && t + 1 < NT) { STG_A(nxtA, t + 1, 1) STG_A(nxtA, t + 1, 3) }
        SB0();
        BAR();
        asm volatile("s_waitcnt lgkmcnt(0)" ::: "memory");
        SB0();
        PH_MFMA(0)
        BAR();

        // ---- P1: kk0, MH1
        PH_READS(0, 1, false)
        SB0();
        BAR();
        asm volatile("s_waitcnt lgkmcnt(0)" ::: "memory");
        SB0();
        PH_MFMA(1)
        BAR();

        // ---- P2: kk1, MH0 (+B kk1)
        PH_READS(1, 0, true)
        SB0();
        BAR();
        asm volatile("s_waitcnt lgkmcnt(0)" ::: "memory");
        SB0();
        PH_MFMA(0)
        BAR();

        // ---- P3: kk1, MH1; stage 6 of tile t+2 into dead regions of cur
        //      (B all rows + A-MH0; last readers were P2, published by its
        //       closing barrier); counted vmcnt(6) drains tile t+1.
        PH_READS(1, 1, false)
        const bool pf = (t + 2 < NT);
        if (pf) {
            STG_B(curB, t + 2, 0) STG_B(curB, t + 2, 1)
            STG_B(curB, t + 2, 2) STG_B(curB, t + 2, 3)
            STG_A(curA, t + 2, 0) STG_A(curA, t + 2, 2)
        }
        SB0();
        BAR();
        asm volatile("s_waitcnt lgkmcnt(0)" ::: "memory");
        SB0();
        if (pf) { asm volatile("s_waitcnt vmcnt(6)" ::: "memory"); }
        else    { asm volatile("s_waitcnt vmcnt(0)" ::: "memory"); }
        SB0();
        PH_MFMA(1)
        BAR();   // tile t+1 resident; its A-MH1 region (cur) now dead
    }

    // epilogue: D row = 4*(lane>>4)+j, col = lane&15
    const int orow0 = row0 + wr * 128 + ((lane >> 4) << 2);
    const int ocol0 = col0 + wc * 64 + frow;
#pragma unroll
    for (int mi = 0; mi < 8; ++mi) {
#pragma unroll
        for (int ni = 0; ni < 4; ++ni) {
#pragma unroll
            for (int j = 0; j < 4; ++j) {
                const int rr = orow0 + mi * 16 + j;
                const int cc = ocol0 + ni * 16;
                C[(size_t)rr * N + cc] = acc[mi][ni][j] * cscale;
            }
        }
    }
}

// ---------------------------------------------------------------------------
// row softmax over f32 S (already scaled /32), in place: writes normalized
// P = exp(s-m)/sum as f16 at the same row base (row stride ncols f32 slots).
__global__ __launch_bounds__(256) void softmax_inplace(
    float* __restrict__ S, int ncols) {
    const int row = blockIdx.x;
    float* srow = S + (size_t)row * ncols;
    const int t = threadIdx.x;

    float x[16];
#pragma unroll
    for (int q = 0; q < 4; ++q) {
        float4 v = *(float4*)(srow + t * 16 + q * 4);
        x[q * 4 + 0] = v.x; x[q * 4 + 1] = v.y;
        x[q * 4 + 2] = v.z; x[q * 4 + 3] = v.w;
    }
    float m = x[0];
#pragma unroll
    for (int j = 1; j < 16; ++j) m = fmaxf(m, x[j]);
#pragma unroll
    for (int off = 32; off; off >>= 1) m = fmaxf(m, __shfl_xor(m, off));
    __shared__ float redm[4];
    if ((t & 63) == 0) redm[t >> 6] = m;
    __syncthreads();
    m = fmaxf(fmaxf(redm[0], redm[1]), fmaxf(redm[2], redm[3]));

    float s = 0.0f;
#pragma unroll
    for (int j = 0; j < 16; ++j) {
        x[j] = __expf(x[j] - m);
        s += x[j];
    }
#pragma unroll
    for (int off = 32; off; off >>= 1) s += __shfl_xor(s, off);
    __shared__ float reds[4];
    if ((t & 63) == 0) reds[t >> 6] = s;
    __syncthreads();
    s = reds[0] + reds[1] + reds[2] + reds[3];
    const float inv = 1.0f / s;

    _Float16* prow = (_Float16*)srow;
    half8 o0, o1;
#pragma unroll
    for (int j = 0; j < 8; ++j) {
        o0[j] = (_Float16)(x[j] * inv);
        o1[j] = (_Float16)(x[8 + j] * inv);
    }
    __syncthreads();
    *(half8*)(prow + t * 16)     = o0;
    *(half8*)(prow + t * 16 + 8) = o1;
}

// ---------------------------------------------------------------------------
extern "C" void kernel_launch(void* const* d_in, const int* in_sizes, int n_in,
                              void* d_out, int out_size, void* d_ws, size_t ws_size,
                              hipStream_t stream) {
    const float* x1 = (const float*)d_in[0];
    const float* x2 = (const float*)d_in[1];
    const float* Wq = (const float*)d_in[2];
    const float* Wk = (const float*)d_in[3];
    const float* Wv = (const float*)d_in[4];
    float* out = (float*)d_out;

    const int NQ = 4096, NKV = 4096, D = 1024;

    // workspace (MB).  S (0..64) overlays buffers dead before the S GEMM.
    char* ws = (char*)d_ws;
    float*    S      = (float*)ws;                       //   0..64
    _Float16* x1cat  = (_Float16*)(ws);                  //   0..24  [4096][3072] A-style (dead after T)
    _Float16* Wqcat  = (_Float16*)(ws + (24u  << 20));   //  24..30  [1024][3072] B-style (dead after Mt)
    _Float16* Wkcat  = (_Float16*)(ws + (30u  << 20));   //  30..36  [1024][3072] A-style (dead after Mt)
    _Float16* Mtcat  = (_Float16*)(ws + (36u  << 20));   //  36..42  [1024][3072] B-style (dead after T)
    _Float16* Wvct   = (_Float16*)(ws + (42u  << 20));   //  42..48  [1024][3072] B-style (dead after V)
    _Float16* x2cat  = (_Float16*)(ws + (64u  << 20));   //  64..88  [4096][3072] B-style (live thru S)
    _Float16* Tcat   = (_Float16*)(ws + (88u  << 20));   //  88..112 [4096][3072] A-style (live thru S)
    _Float16* Vt     = (_Float16*)(ws + (112u << 20));   // 112..120 [1024][4096] f16 (live thru PV)

    // 1) casts: x1 -> A-style, x2 -> B-style; Wk -> A-style, Wq -> B-style;
    //    Wv -> transposed B-style (hi segment used at K=1024)
    split_cast_pair<<<(2 * NQ * D) / 1024, 256, 0, stream>>>(
        x1, x1cat, x2, x2cat, D, NQ * D);
    split_cast_pair<<<(2 * D * D) / 1024, 256, 0, stream>>>(
        Wk, Wkcat, Wq, Wqcat, D, D * D);
    dim3 tb(32, 8), tg(D / 32, D / 32);
    transpose_split_b<<<tg, tb, 0, stream>>>(Wv, Wvct, D);

    // 2) M^T = Wk @ Wq^T  (split-3 in, B-style split out), 8-wave kernel
    gemm_bt8<5><<<dim3(D / 128, D / 128), 512, 0, stream>>>(
        Wkcat, Wqcat, Mtcat, D, D, 3 * D, 3 * D, 3 * D, 1.0f);

    // 3) T = x1 @ M  (A-style split out) -- replaces BOTH Q and K projections
    gemm_bt8<4><<<dim3(D / 128, NQ / 128), 512, 0, stream>>>(
        x1cat, Mtcat, Tcat, NQ, D, 3 * D, 3 * D, 3 * D, 1.0f);

    // 4) V^T: plain f16, K=1024 (hi segments)
    gemm_bt8<1><<<dim3(D / 128, NKV / 128), 512, 0, stream>>>(
        x2cat, Wvct, Vt, NKV, D, D, 3 * D, 3 * D, 1.0f);

    // 5) scores: S = (T @ x2^T)/32 = (Q K^T)/32, K=3072, 256^2 spread kernel
    gemm256_bt_f32<<<dim3(NKV / 256, NQ / 256), 512, 0, stream>>>(
        Tcat, x2cat, S, NQ, NKV, 3 * D, 3 * D, 3 * D, 1.0f / 32.0f);

    // 6) softmax rows in place: f32 scores -> normalized f16 P (stride 8192 f16)
    softmax_inplace<<<NQ, 256, 0, stream>>>(S, NKV);

    // 7) out = P @ V  (A = P f16, lda=8192; B^T = Vt[D][NKV], ldb=4096)
    gemm_bt8<3><<<dim3(D / 128, NQ / 128), 512, 0, stream>>>(
        (const _Float16*)S, Vt, out, NQ, D, NKV, 2 * NKV, NKV, 1.0f);
}